// Round 5
// baseline (446.965 us; speedup 1.0000x reference)
//
#include <hip/hip_runtime.h>
#include <cstdint>
#include <cmath>

typedef __attribute__((ext_vector_type(4))) float f32x4;
typedef __attribute__((ext_vector_type(8))) short s16x8;

#define LOG2E 1.4426950408889634f

__device__ __forceinline__ unsigned short f2bf(float f) {
    unsigned int u = __float_as_uint(f);
    u += 0x7FFFu + ((u >> 16) & 1u);   // round-to-nearest-even
    return (unsigned short)(u >> 16);
}
__device__ __forceinline__ float bf2f(unsigned short s) {
    return __uint_as_float(((unsigned int)s) << 16);
}

// async global->LDS, 16B per lane. LDS dest is wave-uniform base + lane*16.
__device__ __forceinline__ void async_copy16(const void* g, void* l) {
    __builtin_amdgcn_global_load_lds(
        (const __attribute__((address_space(1))) unsigned int*)(uintptr_t)g,
        (__attribute__((address_space(3))) unsigned int*)(uintptr_t)l,
        16, 0, 0);
}

// ---------------- fp32 -> bf16 cast ----------------
__global__ __launch_bounds__(256) void cast_bf16_kernel(const float* __restrict__ in,
                                                        unsigned short* __restrict__ out,
                                                        int n4) {
    int i = blockIdx.x * 256 + threadIdx.x;
    if (i < n4) {
        float4 v = ((const float4*)in)[i];
        ushort4 o;
        o.x = f2bf(v.x); o.y = f2bf(v.y); o.z = f2bf(v.z); o.w = f2bf(v.w);
        ((ushort4*)out)[i] = o;
    }
}

// ---------------- GEMM (128x128 2-phase) — kept for the output projection ----------------
template <bool BF16_OUT>
__global__ __launch_bounds__(256) void gemm_bt(const unsigned short* __restrict__ A,
                                               const unsigned short* __restrict__ B,
                                               const float* __restrict__ bias,
                                               void* __restrict__ Cout,
                                               int M, int N, int K) {
    __shared__ unsigned short As[128 * 64];   // 16 KB
    __shared__ unsigned short Bs[128 * 64];   // 16 KB
    const int tid  = threadIdx.x;
    const int lane = tid & 63;
    const int wv   = tid >> 6;
    const int m0 = blockIdx.y * 128;
    const int n0 = blockIdx.x * 128;
    const int w_row = (wv >> 1) * 64;
    const int w_col = (wv & 1) * 64;
    const int fr = lane & 15;
    const int fg = lane >> 4;
    const int srow = lane >> 3;
    const int scol = ((lane & 7) ^ srow) * 8;
    const int rofs0 = ((fg ^ (fr & 7))) * 8;
    const int rofs1 = rofs0 ^ 32;

    f32x4 acc[4][4];
    const f32x4 zf = {0.f, 0.f, 0.f, 0.f};
    for (int r = 0; r < 4; ++r)
        for (int c = 0; c < 4; ++c) acc[r][c] = zf;

    const unsigned short* gA = A + (size_t)(m0 + wv * 32 + srow) * K + scol;
    const unsigned short* gB = B + (size_t)(n0 + wv * 32 + srow) * K + scol;

    for (int k0 = 0; k0 < K; k0 += 64) {
        for (int i = 0; i < 4; ++i)
            async_copy16(gA + (size_t)i * 8 * K + k0, &As[(wv * 32 + i * 8) * 64]);
        for (int i = 0; i < 4; ++i)
            async_copy16(gB + (size_t)i * 8 * K + k0, &Bs[(wv * 32 + i * 8) * 64]);
        __syncthreads();
        {
            s16x8 af[4], bf[4];
            for (int r = 0; r < 4; ++r)
                af[r] = *(const s16x8*)&As[(w_row + r * 16 + fr) * 64 + rofs0];
            for (int c = 0; c < 4; ++c)
                bf[c] = *(const s16x8*)&Bs[(w_col + c * 16 + fr) * 64 + rofs0];
            for (int r = 0; r < 4; ++r)
                for (int c = 0; c < 4; ++c)
                    acc[r][c] = __builtin_amdgcn_mfma_f32_16x16x32_bf16(af[r], bf[c], acc[r][c], 0, 0, 0);
        }
        {
            s16x8 af[4], bf[4];
            for (int r = 0; r < 4; ++r)
                af[r] = *(const s16x8*)&As[(w_row + r * 16 + fr) * 64 + rofs1];
            for (int c = 0; c < 4; ++c)
                bf[c] = *(const s16x8*)&Bs[(w_col + c * 16 + fr) * 64 + rofs1];
            for (int r = 0; r < 4; ++r)
                for (int c = 0; c < 4; ++c)
                    acc[r][c] = __builtin_amdgcn_mfma_f32_16x16x32_bf16(af[r], bf[c], acc[r][c], 0, 0, 0);
        }
        __syncthreads();
    }

    const int rb = (lane >> 4) * 4;
    for (int c = 0; c < 4; ++c) {
        int col = n0 + w_col + c * 16 + fr;
        float bv = bias[col];
        for (int r = 0; r < 4; ++r) {
            int row = m0 + w_row + r * 16 + rb;
            for (int q = 0; q < 4; ++q) {
                float v = acc[r][c][q] + bv;
                if constexpr (BF16_OUT)
                    ((unsigned short*)Cout)[(size_t)(row + q) * N + col] = f2bf(v);
                else
                    ((float*)Cout)[(size_t)(row + q) * N + col] = v;
            }
        }
    }
}

// ---------------- GEMM 256x256, BK=64, 8 waves — v3: decoupled read/MFMA pipeline ----------
// Per tile t (buf b), quadrant order Q00,Q01,Q11,Q10. Each phase:
//   {setprio(1) MFMA(regs read >=1 phase ago) setprio(0); VMW(6); ds_reads(next); stage; BAR}
// Reads: P1: B1(t) [use P2]; P2: A1(t) [use P3]; P3: none; P4: A0,B0(t+1) from buf^1 [use P1'].
// Staging: P1: AS1(t+1)->buf^1; P2: AS0(t+2); P3: BS0(t+2); P4: BS1(t+2).
// Uniform VMW(6): 6-8 loads in flight; each phase's drain covers the read 1+ phase later.

#define BAR()   __builtin_amdgcn_s_barrier()
#define VMW(N)  asm volatile("s_waitcnt vmcnt(" #N ")" ::: "memory")

#define STAGE2(gXb, XsBuf, rb, kk) \
    async_copy16(gXb + (size_t)(rb) * K + (kk), (void*)&XsBuf[(rb) * 64])

#define ST_AS0(b, kk) { STAGE2(gAb, As[b], rbA_0, kk);      STAGE2(gAb, As[b], rbA_1, kk); }
#define ST_AS1(b, kk) { STAGE2(gAb, As[b], rbA_0 + 64, kk); STAGE2(gAb, As[b], rbA_1 + 64, kk); }
#define ST_BS0(b, kk) { STAGE2(gBb, Bs[b], rbB_0, kk);      STAGE2(gBb, Bs[b], rbB_1, kk); }
#define ST_BS1(b, kk) { STAGE2(gBb, Bs[b], rbB_0 + 32, kk); STAGE2(gBb, Bs[b], rbB_1 + 32, kk); }

#define READ_A(b, mh) \
    _Pragma("unroll") \
    for (int mm_ = 0; mm_ < 4; ++mm_) { \
        const unsigned short* ap_ = &As[b][(wr * 128 + (mh) * 64 + mm_ * 16 + fr) * 64]; \
        Ar[mm_][0] = *(const s16x8*)(ap_ + rofs0); \
        Ar[mm_][1] = *(const s16x8*)(ap_ + rofs1); \
    }

#define READ_B(b, nh, Brg) \
    _Pragma("unroll") \
    for (int nn_ = 0; nn_ < 2; ++nn_) { \
        const unsigned short* bp_ = &Bs[b][(wc * 64 + (nh) * 32 + nn_ * 16 + fr) * 64]; \
        Brg[nn_][0] = *(const s16x8*)(bp_ + rofs0); \
        Brg[nn_][1] = *(const s16x8*)(bp_ + rofs1); \
    }

#define MFMA_Q(mh, nh, Brg) \
    _Pragma("unroll") \
    for (int mm_ = 0; mm_ < 4; ++mm_) { \
        _Pragma("unroll") \
        for (int nn_ = 0; nn_ < 2; ++nn_) { \
            acc[(mh) * 4 + mm_][(nh) * 2 + nn_] = __builtin_amdgcn_mfma_f32_16x16x32_bf16( \
                Ar[mm_][0], Brg[nn_][0], acc[(mh) * 4 + mm_][(nh) * 2 + nn_], 0, 0, 0); \
            acc[(mh) * 4 + mm_][(nh) * 2 + nn_] = __builtin_amdgcn_mfma_f32_16x16x32_bf16( \
                Ar[mm_][1], Brg[nn_][1], acc[(mh) * 4 + mm_][(nh) * 2 + nn_], 0, 0, 0); \
        } \
    }

#define GROUP(b, t) { \
    int x1_ = (t) + 1; if (x1_ >= ktiles) x1_ -= ktiles; \
    int x2_ = (t) + 2; if (x2_ >= ktiles) x2_ -= ktiles; \
    const int kn1 = x1_ << 6; \
    const int kn2 = x2_ << 6; \
    /* P1: Q00 (A0 x B0, regs from P4(t-1)); read B1(t); stage AS1(t+1) */ \
    __builtin_amdgcn_s_setprio(1); MFMA_Q(0, 0, Br0); __builtin_amdgcn_s_setprio(0); \
    VMW(6); \
    READ_B(b, 1, Br1); \
    ST_AS1((b) ^ 1, kn1); \
    BAR(); \
    /* P2: Q01 (A0 x B1); read A1(t) (frees A0 after MFMA); stage AS0(t+2) */ \
    __builtin_amdgcn_s_setprio(1); MFMA_Q(0, 1, Br1); __builtin_amdgcn_s_setprio(0); \
    VMW(6); \
    READ_A(b, 1); \
    ST_AS0(b, kn2); \
    BAR(); \
    /* P3: Q11 (A1 x B1); stage BS0(t+2) */ \
    __builtin_amdgcn_s_setprio(1); MFMA_Q(1, 1, Br1); __builtin_amdgcn_s_setprio(0); \
    VMW(6); \
    ST_BS0(b, kn2); \
    BAR(); \
    /* P4: Q10 (A1 x B0); read A0,B0 of tile t+1 from buf^1; stage BS1(t+2) */ \
    __builtin_amdgcn_s_setprio(1); MFMA_Q(1, 0, Br0); __builtin_amdgcn_s_setprio(0); \
    VMW(6); \
    READ_A((b) ^ 1, 0); \
    READ_B((b) ^ 1, 0, Br0); \
    ST_BS1(b, kn2); \
    BAR(); \
}

__global__ __launch_bounds__(512, 2) void gemm256_bt(const unsigned short* __restrict__ A,
                                                     const unsigned short* __restrict__ B,
                                                     const float* __restrict__ bias,
                                                     unsigned short* __restrict__ C,
                                                     int M, int N, int K) {
    __shared__ unsigned short As[2][256 * 64];   // 64 KB
    __shared__ unsigned short Bs[2][256 * 64];   // 64 KB
    const int tid  = threadIdx.x;
    const int lane = tid & 63;
    const int wv   = tid >> 6;      // 0..7
    const int wr   = wv >> 2;       // 0..1 (M-half)
    const int wc   = wv & 3;        // 0..3 (N-quarter)
    // XCD-aware chunked mapping (round-robin dispatch: xcd = bid&7).
    // Each XCD: 2 A-strips x 15 B-panels; each B-panel shared by 2 co-XCD blocks.
    const int j     = blockIdx.x & 7;
    const int local = blockIdx.x >> 3;
    const int strip = 2 * (j & 3) + (local & 1);
    const int panel = (j >> 2) * 15 + (local >> 1);
    const int m0 = strip * 256;
    const int n0 = panel * 256;
    const int fr = lane & 15;
    const int fg = lane >> 4;
    const int rofs0 = (fg ^ (fr & 7)) * 8;
    const int rofs1 = rofs0 ^ 32;
    // staging: lane covers row (lane>>3), fetches global chunk (lane&7)^((lane>>3)&7)
    const int rlane = lane >> 3;
    const int swzc  = ((lane & 7) ^ (rlane & 7)) * 8;
    const int idx0 = wv * 2, idx1 = wv * 2 + 1;
    const int rbA_0 = idx0 * 8 + ((idx0 >= 8) ? 64 : 0);  // A-S0 row bases
    const int rbA_1 = idx1 * 8 + ((idx1 >= 8) ? 64 : 0);
    const int rbB_0 = (idx0 >> 2) * 64 + (idx0 & 3) * 8;  // B-S0 row bases
    const int rbB_1 = (idx1 >> 2) * 64 + (idx1 & 3) * 8;
    const int ktiles = K >> 6;      // 40

    const unsigned short* gAb = A + (size_t)(m0 + rlane) * K + swzc;
    const unsigned short* gBb = B + (size_t)(n0 + rlane) * K + swzc;

    f32x4 acc[8][4];
    const f32x4 zf = {0.f, 0.f, 0.f, 0.f};
#pragma unroll
    for (int i = 0; i < 8; ++i)
#pragma unroll
        for (int jj = 0; jj < 4; ++jj) acc[i][jj] = zf;

    s16x8 Ar[4][2], Br0[2][2], Br1[2][2];

    // prologue: tile0 complete + tile1 {AS0, BS0, BS1} (AS1(1) comes in P1 of GROUP 0);
    // drain tile0 (VMW(6) leaves tile1's 6 in flight); pre-read A0(t0), B0(t0).
    ST_AS0(0, 0); ST_AS1(0, 0); ST_BS0(0, 0); ST_BS1(0, 0);
    ST_AS0(1, 64); ST_BS0(1, 64); ST_BS1(1, 64);
    VMW(6);
    BAR();
    READ_A(0, 0);
    READ_B(0, 0, Br0);

    const int nit = ktiles >> 1;
    for (int it = 0; it < nit; ++it) {
        GROUP(0, it * 2);
        GROUP(1, it * 2 + 1);
    }

    // epilogue: C/D layout col=lane&15, row=(lane>>4)*4+reg
    const int rb = (lane >> 4) * 4;
#pragma unroll
    for (int nn = 0; nn < 4; ++nn) {
        int col = n0 + wc * 64 + nn * 16 + fr;
        float bv = bias[col];
#pragma unroll
        for (int mm = 0; mm < 8; ++mm) {
            int row = m0 + wr * 128 + mm * 16 + rb;
#pragma unroll
            for (int q = 0; q < 4; ++q) {
                float v = acc[mm][nn][q] + bv;
                C[(size_t)(row + q) * N + col] = f2bf(v);
            }
        }
    }
}

// ---------------- RoPE in-place on q-half only (k handled in rope_pack_k) ----------------
__global__ __launch_bounds__(256) void rope_q_kernel(unsigned short* __restrict__ qkv) {
    int g = blockIdx.x * 256 + threadIdx.x;  // 2048*32*2 items
    int c = g & 1;            // half-chunk: pairs d0..d0+7
    int h = (g >> 1) & 31;
    int p = g >> 6;
    size_t base = (size_t)p * 7680 + h * 80 + c * 8;
    s16x8 x1v = *(const s16x8*)(qkv + base);
    s16x8 x2v = *(const s16x8*)(qkv + base + 16);
    s16x8 o1, o2;
    for (int j = 0; j < 8; ++j) {
        int dp = c * 8 + j;
        float freq = expf(-(float)dp * 0.57564627324851142f);  // ln(10000)/16
        float sn, cs;
        sincosf((float)p * freq, &sn, &cs);
        float x1 = bf2f((unsigned short)x1v[j]);
        float x2 = bf2f((unsigned short)x2v[j]);
        o1[j] = (short)f2bf(x1 * cs - x2 * sn);
        o2[j] = (short)f2bf(x1 * sn + x2 * cs);
    }
    *(s16x8*)(qkv + base)      = o1;
    *(s16x8*)(qkv + base + 16) = o2;
}

// ---------------- fused k-RoPE + pack: qkv k-half -> Kp[h][key][96] ----------------
__global__ __launch_bounds__(256) void rope_pack_k_kernel(const unsigned short* __restrict__ qkv,
                                                          unsigned short* __restrict__ Kp) {
    int g = blockIdx.x * 256 + threadIdx.x;  // 2048*32*12
    int c   = g % 12;
    int h   = (g / 12) & 31;
    int pos = g / 384;
    int d0 = c * 8;
    const unsigned short* kb = qkv + (size_t)pos * 7680 + 2560 + h * 80;
    s16x8 v = {0, 0, 0, 0, 0, 0, 0, 0};
    if (c >= 4) {
        if (d0 < 80) v = *(const s16x8*)(kb + d0);
    } else if (c < 2) {          // x1 side: out = x1*cos - x2*sin
        s16x8 x1v = *(const s16x8*)(kb + d0);
        s16x8 x2v = *(const s16x8*)(kb + d0 + 16);
        for (int j = 0; j < 8; ++j) {
            int dp = d0 + j;
            float freq = expf(-(float)dp * 0.57564627324851142f);
            float sn, cs;
            sincosf((float)pos * freq, &sn, &cs);
            v[j] = (short)f2bf(bf2f((unsigned short)x1v[j]) * cs -
                               bf2f((unsigned short)x2v[j]) * sn);
        }
    } else {                     // x2 side: out = x1*sin + x2*cos
        s16x8 x1v = *(const s16x8*)(kb + d0 - 16);
        s16x8 x2v = *(const s16x8*)(kb + d0);
        for (int j = 0; j < 8; ++j) {
            int dp = d0 - 16 + j;
            float freq = expf(-(float)dp * 0.57564627324851142f);
            float sn, cs;
            sincosf((float)pos * freq, &sn, &cs);
            v[j] = (short)f2bf(bf2f((unsigned short)x1v[j]) * sn +
                               bf2f((unsigned short)x2v[j]) * cs);
        }
    }
    *(s16x8*)(Kp + ((size_t)h * 2048 + pos) * 96 + d0) = v;
}

// ---------------- pack V^T tiled: qkv v-half -> Vp[h][kblk16][80][16] ----------------
__global__ __launch_bounds__(256) void pack_v_kernel(const unsigned short* __restrict__ qkv,
                                                     unsigned short* __restrict__ Vp) {
    int h  = blockIdx.x & 31;
    int g64 = blockIdx.x >> 5;           // 0..31
    int k0 = g64 * 64;
    int tid = threadIdx.x;
    for (int ci = tid; ci < 320; ci += 256) {   // (kbl 0..3) x (d 0..79)
        int d   = ci % 80;
        int kbl = ci / 80;
        unsigned short tmp[16];
        for (int j = 0; j < 16; ++j)
            tmp[j] = qkv[(size_t)(k0 + kbl * 16 + j) * 7680 + 5120 + h * 80 + d];
        unsigned short* dst = Vp + ((size_t)h * 128 + g64 * 4 + kbl) * 1280 + d * 16;
        *(s16x8*)dst       = *(const s16x8*)&tmp[0];
        *(s16x8*)(dst + 8) = *(const s16x8*)&tmp[8];
    }
}

// ---------------- flash attention v5: balanced combined-strip schedule ----------------
// Block = head h x strip-pair {p, 127-p}: combined causal work is ALWAYS 129 16-key tiles
// = 65 32-key units. All 4 waves take a contiguous 65/4 slice of the concatenated unit
// list (strip 127-p first, then strip p); at most one wave straddles (reloads Q frags).
// Per-strip partials merged via LDS float atomicAdd (2-way bank aliasing = free);
// symmetric 4-wave epilogue normalizes. Max per-wave work: 17 units (was 64 tiles at p=0).
__global__ __launch_bounds__(256) void flash3_kernel(const unsigned short* __restrict__ qkv,
                                                     const unsigned short* __restrict__ Kp,
                                                     const unsigned short* __restrict__ Vp,
                                                     unsigned short* __restrict__ attn) {
    __shared__ unsigned short Pt[4][640];      // per-wave 16x40 P tile
    __shared__ float parts_s[2][16][84];       // per-strip O accumulators (pitch 84)
    __shared__ float parts_l[2][16];           // per-strip row-sum accumulators
    const int tid  = threadIdx.x;
    const int lane = tid & 63;
    const int wv   = tid >> 6;
    const int h = blockIdx.x & 31;
    const int p = blockIdx.x >> 5;             // 0..63
    const int fr = lane & 15;
    const int fg = lane >> 4;
    const float k1 = 0.11180339887498949f * LOG2E;  // (1/sqrt(80)) * log2(e)

    for (int i = tid; i < 2 * 16 * 84; i += 256) ((float*)parts_s)[i] = 0.f;
    if (tid < 32) ((float*)parts_l)[tid] = 0.f;
    __syncthreads();

    // combined schedule: strips s1=127-p (n1 tiles) then s0=p (n0 tiles), in 32-key units.
    // U = ceil(n1/2)+ceil(n0/2) = 65 for every p. Wave w: units [w*U/4, (w+1)*U/4).
    const int n1 = 128 - p;
    const int U1 = (n1 + 1) >> 1;
    const int U  = U1 + ((p + 2) >> 1);        // 65
    const int lo = (wv * U) >> 2;
    const int hi = ((wv + 1) * U) >> 2;
    const int a1 = (lo < U1) ? lo : U1;
    const int b1 = (hi < U1) ? hi : U1;
    const int a0 = (lo > U1) ? (lo - U1) : 0;
    const int b0 = (hi > U1) ? (hi - U1) : 0;

    f32x4 O[5];
    const f32x4 zf = {0.f, 0.f, 0.f, 0.f};
    const s16x8 zs = {0, 0, 0, 0, 0, 0, 0, 0};
    for (int t = 0; t < 5; ++t) O[t] = zf;
    float rs[4] = {0.f, 0.f, 0.f, 0.f};
    unsigned short* Pw = &Pt[wv][0];

    for (int seg = 0; seg < 2; ++seg) {
        const int s_   = seg ? p : (127 - p);
        const int slot = seg ? 0 : 1;
        const int ua   = seg ? a0 : a1;
        const int ub   = seg ? b0 : b1;
        if (ua >= ub) continue;
        const int sm16 = s_ * 16;
        const int kend = sm16 + 16;            // causal key limit for this strip

        s16x8 qf[3];
        {
            const unsigned short* qb = qkv + (size_t)(sm16 + fr) * 7680 + h * 80;
            for (int sd = 0; sd < 3; ++sd) {
                int d = 32 * sd + fg * 8;
                qf[sd] = (d < 80) ? *(const s16x8*)(qb + d) : zs;
            }
        }
        const unsigned short* kptr = Kp + (size_t)h * 2048 * 96 + (size_t)(ua * 32 + fr) * 96 + fg * 8;
        const unsigned short* vptr = Vp + (size_t)h * 128 * 1280 + (size_t)(ua * 2) * 1280
                                     + (fg >> 1) * 1280 + fr * 16 + (fg & 1) * 8;

        for (int u = ua; u < ub; ++u) {
            const int k0 = u * 32;
            s16x8 kb[2][3];
            for (int g = 0; g < 2; ++g)
                for (int sd = 0; sd < 3; ++sd)
                    kb[g][sd] = *(const s16x8*)(kptr + g * 1536 + sd * 32);
            s16x8 vb[5];
            for (int t = 0; t < 5; ++t)
                vb[t] = *(const s16x8*)(vptr + t * 256);

            f32x4 sa[2] = {zf, zf};
            __builtin_amdgcn_s_setprio(1);
            for (int g = 0; g < 2; ++g)
                for (int sd = 0; sd < 3; ++sd)
                    sa[g] = __builtin_amdgcn_mfma_f32_16x16x32_bf16(qf[sd], kb[g][sd], sa[g], 0, 0, 0);
            __builtin_amdgcn_s_setprio(0);

            if (k0 + 32 > sm16 || k0 + 32 > kend) {
                for (int g = 0; g < 2; ++g)
                    for (int r = 0; r < 4; ++r) {
                        int key  = k0 + g * 16 + fr;
                        int qrow = sm16 + fg * 4 + r;
                        if (key > qrow || key >= kend) sa[g][r] = -1e30f;
                    }
            }
            float pr[2][4];
            for (int g = 0; g < 2; ++g)
                for (int r = 0; r < 4; ++r)
                    pr[g][r] = __builtin_amdgcn_exp2f(sa[g][r] * k1);
            for (int r = 0; r < 4; ++r) rs[r] += pr[0][r] + pr[1][r];
            for (int g = 0; g < 2; ++g)
                for (int r = 0; r < 4; ++r)
                    Pw[(fg * 4 + r) * 40 + g * 16 + fr] =
                        (unsigned short)(__float_as_uint(pr[g][r]) >> 16);

            s16x8 pa = *(const s16x8*)(Pw + fr * 40 + fg * 8);
            __builtin_amdgcn_s_setprio(1);
            for (int t = 0; t < 5; ++t)
                O[t] = __builtin_amdgcn_mfma_f32_16x16x32_bf16(pa, vb[t], O[t], 0, 0, 0);
            __builtin_amdgcn_s_setprio(0);

            kptr += 3072;   // 32 keys * 96
            vptr += 2560;   // 2 blocks * 1280
        }

        // flush this strip's partials
        for (int r = 0; r < 4; ++r) {
            float v = rs[r];
            v += __shfl_xor(v, 1);
            v += __shfl_xor(v, 2);
            v += __shfl_xor(v, 4);
            v += __shfl_xor(v, 8);
            rs[r] = v;
        }
        if (fr == 0)
            for (int r = 0; r < 4; ++r)
                atomicAdd(&parts_l[slot][fg * 4 + r], rs[r]);
        for (int t = 0; t < 5; ++t)
            for (int r = 0; r < 4; ++r)
                atomicAdd(&parts_s[slot][fg * 4 + r][t * 16 + fr], O[t][r]);
        for (int t = 0; t < 5; ++t) O[t] = zf;
        for (int r = 0; r < 4; ++r) rs[r] = 0.f;
    }

    __syncthreads();
    // epilogue: wave w writes combined rows [w*8, w*8+8); rows 0..15 -> strip p, 16..31 -> 127-p
    {
        const int ri    = wv * 8 + (lane >> 3);
        const int strip = ri >> 4;
        const int row16 = ri & 15;
        const int grow  = (strip ? (127 - p) : p) * 16 + row16;
        const float rl  = 1.0f / parts_l[strip][row16];
        const int c0 = lane & 7;
        for (int i = 0; i < 10; ++i) {
            int col = c0 + 8 * i;
            float v = parts_s[strip][row16][col] * rl;
            attn[(size_t)grow * 2560 + h * 80 + col] = f2bf(v);
        }
    }
}

extern "C" void kernel_launch(void* const* d_in, const int* in_sizes, int n_in,
                              void* d_out, int out_size, void* d_ws, size_t ws_size,
                              hipStream_t stream) {
    const float* x    = (const float*)d_in[0];
    const float* wqkv = (const float*)d_in[1];
    const float* bqkv = (const float*)d_in[2];
    const float* outw = (const float*)d_in[3];
    const float* outb = (const float*)d_in[4];

    unsigned short* xb    = (unsigned short*)d_ws;                  // 2048*2560
    unsigned short* wqkvb = xb + (size_t)2048 * 2560;               // 7680*2560 (dead after gemm1)
    unsigned short* Kp    = wqkvb;                                  // 32*2048*96   (aliases wqkvb)
    unsigned short* Vp    = wqkvb + (size_t)32 * 2048 * 96;         // 32*128*1280  (aliases wqkvb)
    unsigned short* outwb = wqkvb + (size_t)7680 * 2560;            // 2560*2560
    unsigned short* qkvb  = outwb + (size_t)2560 * 2560;            // 2048*7680
    unsigned short* attnb = qkvb  + (size_t)2048 * 7680;            // 2048*2560
    float* out = (float*)d_out;

    cast_bf16_kernel<<<2048 * 2560 / 4 / 256, 256, 0, stream>>>(x, xb, 2048 * 2560 / 4);
    cast_bf16_kernel<<<7680 * 2560 / 4 / 256, 256, 0, stream>>>(wqkv, wqkvb, 7680 * 2560 / 4);
    cast_bf16_kernel<<<2560 * 2560 / 4 / 256, 256, 0, stream>>>(outw, outwb, 2560 * 2560 / 4);

    // qkv projection: 256x256 v3 pipeline, 240 blocks, XCD-chunked panel-sharing map
    gemm256_bt<<<240, 512, 0, stream>>>(xb, wqkvb, bqkv, qkvb, 2048, 7680, 2560);

    rope_q_kernel<<<2048 * 64 / 256, 256, 0, stream>>>(qkvb);
    rope_pack_k_kernel<<<2048 * 384 / 256, 256, 0, stream>>>(qkvb, Kp);
    pack_v_kernel<<<32 * 32, 256, 0, stream>>>(qkvb, Vp);

    flash3_kernel<<<2048, 256, 0, stream>>>(qkvb, Kp, Vp, attnb);

    gemm_bt<false><<<dim3(2560 / 128, 2048 / 128), 256, 0, stream>>>(
        attnb, outwb, outb, (void*)out, 2048, 2560, 2560);
}

// Round 6
// 416.033 us; speedup vs baseline: 1.0743x; 1.0743x over previous
//
#include <hip/hip_runtime.h>
#include <cstdint>
#include <cmath>

typedef __attribute__((ext_vector_type(4))) float f32x4;
typedef __attribute__((ext_vector_type(8))) short s16x8;

#define LOG2E 1.4426950408889634f

__device__ __forceinline__ unsigned short f2bf(float f) {
    unsigned int u = __float_as_uint(f);
    u += 0x7FFFu + ((u >> 16) & 1u);   // round-to-nearest-even
    return (unsigned short)(u >> 16);
}
__device__ __forceinline__ float bf2f(unsigned short s) {
    return __uint_as_float(((unsigned int)s) << 16);
}

// async global->LDS, 16B per lane. LDS dest is wave-uniform base + lane*16.
__device__ __forceinline__ void async_copy16(const void* g, void* l) {
    __builtin_amdgcn_global_load_lds(
        (const __attribute__((address_space(1))) unsigned int*)(uintptr_t)g,
        (__attribute__((address_space(3))) unsigned int*)(uintptr_t)l,
        16, 0, 0);
}

// ---------------- fp32 -> bf16 cast ----------------
__global__ __launch_bounds__(256) void cast_bf16_kernel(const float* __restrict__ in,
                                                        unsigned short* __restrict__ out,
                                                        int n4) {
    int i = blockIdx.x * 256 + threadIdx.x;
    if (i < n4) {
        float4 v = ((const float4*)in)[i];
        ushort4 o;
        o.x = f2bf(v.x); o.y = f2bf(v.y); o.z = f2bf(v.z); o.w = f2bf(v.w);
        ((ushort4*)out)[i] = o;
    }
}

// ---------------- GEMM (128x128 2-phase) — kept for the output projection ----------------
template <bool BF16_OUT>
__global__ __launch_bounds__(256) void gemm_bt(const unsigned short* __restrict__ A,
                                               const unsigned short* __restrict__ B,
                                               const float* __restrict__ bias,
                                               void* __restrict__ Cout,
                                               int M, int N, int K) {
    __shared__ unsigned short As[128 * 64];   // 16 KB
    __shared__ unsigned short Bs[128 * 64];   // 16 KB
    const int tid  = threadIdx.x;
    const int lane = tid & 63;
    const int wv   = tid >> 6;
    const int m0 = blockIdx.y * 128;
    const int n0 = blockIdx.x * 128;
    const int w_row = (wv >> 1) * 64;
    const int w_col = (wv & 1) * 64;
    const int fr = lane & 15;
    const int fg = lane >> 4;
    const int srow = lane >> 3;
    const int scol = ((lane & 7) ^ srow) * 8;
    const int rofs0 = ((fg ^ (fr & 7))) * 8;
    const int rofs1 = rofs0 ^ 32;

    f32x4 acc[4][4];
    const f32x4 zf = {0.f, 0.f, 0.f, 0.f};
    for (int r = 0; r < 4; ++r)
        for (int c = 0; c < 4; ++c) acc[r][c] = zf;

    const unsigned short* gA = A + (size_t)(m0 + wv * 32 + srow) * K + scol;
    const unsigned short* gB = B + (size_t)(n0 + wv * 32 + srow) * K + scol;

    for (int k0 = 0; k0 < K; k0 += 64) {
        for (int i = 0; i < 4; ++i)
            async_copy16(gA + (size_t)i * 8 * K + k0, &As[(wv * 32 + i * 8) * 64]);
        for (int i = 0; i < 4; ++i)
            async_copy16(gB + (size_t)i * 8 * K + k0, &Bs[(wv * 32 + i * 8) * 64]);
        __syncthreads();
        {
            s16x8 af[4], bf[4];
            for (int r = 0; r < 4; ++r)
                af[r] = *(const s16x8*)&As[(w_row + r * 16 + fr) * 64 + rofs0];
            for (int c = 0; c < 4; ++c)
                bf[c] = *(const s16x8*)&Bs[(w_col + c * 16 + fr) * 64 + rofs0];
            for (int r = 0; r < 4; ++r)
                for (int c = 0; c < 4; ++c)
                    acc[r][c] = __builtin_amdgcn_mfma_f32_16x16x32_bf16(af[r], bf[c], acc[r][c], 0, 0, 0);
        }
        {
            s16x8 af[4], bf[4];
            for (int r = 0; r < 4; ++r)
                af[r] = *(const s16x8*)&As[(w_row + r * 16 + fr) * 64 + rofs1];
            for (int c = 0; c < 4; ++c)
                bf[c] = *(const s16x8*)&Bs[(w_col + c * 16 + fr) * 64 + rofs1];
            for (int r = 0; r < 4; ++r)
                for (int c = 0; c < 4; ++c)
                    acc[r][c] = __builtin_amdgcn_mfma_f32_16x16x32_bf16(af[r], bf[c], acc[r][c], 0, 0, 0);
        }
        __syncthreads();
    }

    const int rb = (lane >> 4) * 4;
    for (int c = 0; c < 4; ++c) {
        int col = n0 + w_col + c * 16 + fr;
        float bv = bias[col];
        for (int r = 0; r < 4; ++r) {
            int row = m0 + w_row + r * 16 + rb;
            for (int q = 0; q < 4; ++q) {
                float v = acc[r][c][q] + bv;
                if constexpr (BF16_OUT)
                    ((unsigned short*)Cout)[(size_t)(row + q) * N + col] = f2bf(v);
                else
                    ((float*)Cout)[(size_t)(row + q) * N + col] = v;
            }
        }
    }
}

// ---------------- GEMM 256x256, BK=64, 8 waves — v3: decoupled read/MFMA pipeline ----------
// Per tile t (buf b), quadrant order Q00,Q01,Q11,Q10. Each phase:
//   {setprio(1) MFMA(regs read >=1 phase ago) setprio(0); VMW(6); ds_reads(next); stage; BAR}
// Reads: P1: B1(t) [use P2]; P2: A1(t) [use P3]; P3: none; P4: A0,B0(t+1) from buf^1 [use P1'].
// Staging: P1: AS1(t+1)->buf^1; P2: AS0(t+2); P3: BS0(t+2); P4: BS1(t+2).
// Uniform VMW(6): 6-8 loads in flight; each phase's drain covers the read 1+ phase later.

#define BAR()   __builtin_amdgcn_s_barrier()
#define VMW(N)  asm volatile("s_waitcnt vmcnt(" #N ")" ::: "memory")

#define STAGE2(gXb, XsBuf, rb, kk) \
    async_copy16(gXb + (size_t)(rb) * K + (kk), (void*)&XsBuf[(rb) * 64])

#define ST_AS0(b, kk) { STAGE2(gAb, As[b], rbA_0, kk);      STAGE2(gAb, As[b], rbA_1, kk); }
#define ST_AS1(b, kk) { STAGE2(gAb, As[b], rbA_0 + 64, kk); STAGE2(gAb, As[b], rbA_1 + 64, kk); }
#define ST_BS0(b, kk) { STAGE2(gBb, Bs[b], rbB_0, kk);      STAGE2(gBb, Bs[b], rbB_1, kk); }
#define ST_BS1(b, kk) { STAGE2(gBb, Bs[b], rbB_0 + 32, kk); STAGE2(gBb, Bs[b], rbB_1 + 32, kk); }

#define READ_A(b, mh) \
    _Pragma("unroll") \
    for (int mm_ = 0; mm_ < 4; ++mm_) { \
        const unsigned short* ap_ = &As[b][(wr * 128 + (mh) * 64 + mm_ * 16 + fr) * 64]; \
        Ar[mm_][0] = *(const s16x8*)(ap_ + rofs0); \
        Ar[mm_][1] = *(const s16x8*)(ap_ + rofs1); \
    }

#define READ_B(b, nh, Brg) \
    _Pragma("unroll") \
    for (int nn_ = 0; nn_ < 2; ++nn_) { \
        const unsigned short* bp_ = &Bs[b][(wc * 64 + (nh) * 32 + nn_ * 16 + fr) * 64]; \
        Brg[nn_][0] = *(const s16x8*)(bp_ + rofs0); \
        Brg[nn_][1] = *(const s16x8*)(bp_ + rofs1); \
    }

#define MFMA_Q(mh, nh, Brg) \
    _Pragma("unroll") \
    for (int mm_ = 0; mm_ < 4; ++mm_) { \
        _Pragma("unroll") \
        for (int nn_ = 0; nn_ < 2; ++nn_) { \
            acc[(mh) * 4 + mm_][(nh) * 2 + nn_] = __builtin_amdgcn_mfma_f32_16x16x32_bf16( \
                Ar[mm_][0], Brg[nn_][0], acc[(mh) * 4 + mm_][(nh) * 2 + nn_], 0, 0, 0); \
            acc[(mh) * 4 + mm_][(nh) * 2 + nn_] = __builtin_amdgcn_mfma_f32_16x16x32_bf16( \
                Ar[mm_][1], Brg[nn_][1], acc[(mh) * 4 + mm_][(nh) * 2 + nn_], 0, 0, 0); \
        } \
    }

#define GROUP(b, t) { \
    int x1_ = (t) + 1; if (x1_ >= ktiles) x1_ -= ktiles; \
    int x2_ = (t) + 2; if (x2_ >= ktiles) x2_ -= ktiles; \
    const int kn1 = x1_ << 6; \
    const int kn2 = x2_ << 6; \
    /* P1: Q00 (A0 x B0, regs from P4(t-1)); read B1(t); stage AS1(t+1) */ \
    __builtin_amdgcn_s_setprio(1); MFMA_Q(0, 0, Br0); __builtin_amdgcn_s_setprio(0); \
    VMW(6); \
    READ_B(b, 1, Br1); \
    ST_AS1((b) ^ 1, kn1); \
    BAR(); \
    /* P2: Q01 (A0 x B1); read A1(t) (frees A0 after MFMA); stage AS0(t+2) */ \
    __builtin_amdgcn_s_setprio(1); MFMA_Q(0, 1, Br1); __builtin_amdgcn_s_setprio(0); \
    VMW(6); \
    READ_A(b, 1); \
    ST_AS0(b, kn2); \
    BAR(); \
    /* P3: Q11 (A1 x B1); stage BS0(t+2) */ \
    __builtin_amdgcn_s_setprio(1); MFMA_Q(1, 1, Br1); __builtin_amdgcn_s_setprio(0); \
    VMW(6); \
    ST_BS0(b, kn2); \
    BAR(); \
    /* P4: Q10 (A1 x B0); read A0,B0 of tile t+1 from buf^1; stage BS1(t+2) */ \
    __builtin_amdgcn_s_setprio(1); MFMA_Q(1, 0, Br0); __builtin_amdgcn_s_setprio(0); \
    VMW(6); \
    READ_A((b) ^ 1, 0); \
    READ_B((b) ^ 1, 0, Br0); \
    ST_BS1(b, kn2); \
    BAR(); \
}

__global__ __launch_bounds__(512, 2) void gemm256_bt(const unsigned short* __restrict__ A,
                                                     const unsigned short* __restrict__ B,
                                                     const float* __restrict__ bias,
                                                     unsigned short* __restrict__ C,
                                                     int M, int N, int K) {
    __shared__ unsigned short As[2][256 * 64];   // 64 KB
    __shared__ unsigned short Bs[2][256 * 64];   // 64 KB
    const int tid  = threadIdx.x;
    const int lane = tid & 63;
    const int wv   = tid >> 6;      // 0..7
    const int wr   = wv >> 2;       // 0..1 (M-half)
    const int wc   = wv & 3;        // 0..3 (N-quarter)
    // XCD-aware chunked mapping (round-robin dispatch: xcd = bid&7).
    // Each XCD: 2 A-strips x 15 B-panels; each B-panel shared by 2 co-XCD blocks.
    const int j     = blockIdx.x & 7;
    const int local = blockIdx.x >> 3;
    const int strip = 2 * (j & 3) + (local & 1);
    const int panel = (j >> 2) * 15 + (local >> 1);
    const int m0 = strip * 256;
    const int n0 = panel * 256;
    const int fr = lane & 15;
    const int fg = lane >> 4;
    const int rofs0 = (fg ^ (fr & 7)) * 8;
    const int rofs1 = rofs0 ^ 32;
    // staging: lane covers row (lane>>3), fetches global chunk (lane&7)^((lane>>3)&7)
    const int rlane = lane >> 3;
    const int swzc  = ((lane & 7) ^ (rlane & 7)) * 8;
    const int idx0 = wv * 2, idx1 = wv * 2 + 1;
    const int rbA_0 = idx0 * 8 + ((idx0 >= 8) ? 64 : 0);  // A-S0 row bases
    const int rbA_1 = idx1 * 8 + ((idx1 >= 8) ? 64 : 0);
    const int rbB_0 = (idx0 >> 2) * 64 + (idx0 & 3) * 8;  // B-S0 row bases
    const int rbB_1 = (idx1 >> 2) * 64 + (idx1 & 3) * 8;
    const int ktiles = K >> 6;      // 40

    const unsigned short* gAb = A + (size_t)(m0 + rlane) * K + swzc;
    const unsigned short* gBb = B + (size_t)(n0 + rlane) * K + swzc;

    f32x4 acc[8][4];
    const f32x4 zf = {0.f, 0.f, 0.f, 0.f};
#pragma unroll
    for (int i = 0; i < 8; ++i)
#pragma unroll
        for (int jj = 0; jj < 4; ++jj) acc[i][jj] = zf;

    s16x8 Ar[4][2], Br0[2][2], Br1[2][2];

    // prologue: tile0 complete + tile1 {AS0, BS0, BS1} (AS1(1) comes in P1 of GROUP 0);
    // drain tile0 (VMW(6) leaves tile1's 6 in flight); pre-read A0(t0), B0(t0).
    ST_AS0(0, 0); ST_AS1(0, 0); ST_BS0(0, 0); ST_BS1(0, 0);
    ST_AS0(1, 64); ST_BS0(1, 64); ST_BS1(1, 64);
    VMW(6);
    BAR();
    READ_A(0, 0);
    READ_B(0, 0, Br0);

    const int nit = ktiles >> 1;
    for (int it = 0; it < nit; ++it) {
        GROUP(0, it * 2);
        GROUP(1, it * 2 + 1);
    }

    // epilogue: C/D layout col=lane&15, row=(lane>>4)*4+reg
    const int rb = (lane >> 4) * 4;
#pragma unroll
    for (int nn = 0; nn < 4; ++nn) {
        int col = n0 + wc * 64 + nn * 16 + fr;
        float bv = bias[col];
#pragma unroll
        for (int mm = 0; mm < 8; ++mm) {
            int row = m0 + wr * 128 + mm * 16 + rb;
#pragma unroll
            for (int q = 0; q < 4; ++q) {
                float v = acc[mm][nn][q] + bv;
                C[(size_t)(row + q) * N + col] = f2bf(v);
            }
        }
    }
}

// ---------------- RoPE in-place on q-half only (k handled in rope_pack_k) ----------------
__global__ __launch_bounds__(256) void rope_q_kernel(unsigned short* __restrict__ qkv) {
    int g = blockIdx.x * 256 + threadIdx.x;  // 2048*32*2 items
    int c = g & 1;            // half-chunk: pairs d0..d0+7
    int h = (g >> 1) & 31;
    int p = g >> 6;
    size_t base = (size_t)p * 7680 + h * 80 + c * 8;
    s16x8 x1v = *(const s16x8*)(qkv + base);
    s16x8 x2v = *(const s16x8*)(qkv + base + 16);
    s16x8 o1, o2;
    for (int j = 0; j < 8; ++j) {
        int dp = c * 8 + j;
        float freq = expf(-(float)dp * 0.57564627324851142f);  // ln(10000)/16
        float sn, cs;
        sincosf((float)p * freq, &sn, &cs);
        float x1 = bf2f((unsigned short)x1v[j]);
        float x2 = bf2f((unsigned short)x2v[j]);
        o1[j] = (short)f2bf(x1 * cs - x2 * sn);
        o2[j] = (short)f2bf(x1 * sn + x2 * cs);
    }
    *(s16x8*)(qkv + base)      = o1;
    *(s16x8*)(qkv + base + 16) = o2;
}

// ---------------- fused k-RoPE + pack: qkv k-half -> Kp[h][u32][12][32][8] ----------------
// Chunk-major per 32-key tile so flash can (a) stage linearly with global_load_lds and
// (b) read MFMA fragments from LDS at the bank-throughput floor.
__global__ __launch_bounds__(256) void rope_pack_k_kernel(const unsigned short* __restrict__ qkv,
                                                          unsigned short* __restrict__ Kp) {
    int g = blockIdx.x * 256 + threadIdx.x;  // 2048*32*12
    int c   = g % 12;
    int h   = (g / 12) & 31;
    int pos = g / 384;
    int d0 = c * 8;
    const unsigned short* kb = qkv + (size_t)pos * 7680 + 2560 + h * 80;
    s16x8 v = {0, 0, 0, 0, 0, 0, 0, 0};
    if (c >= 4) {
        if (d0 < 80) v = *(const s16x8*)(kb + d0);
    } else if (c < 2) {          // x1 side: out = x1*cos - x2*sin
        s16x8 x1v = *(const s16x8*)(kb + d0);
        s16x8 x2v = *(const s16x8*)(kb + d0 + 16);
        for (int j = 0; j < 8; ++j) {
            int dp = d0 + j;
            float freq = expf(-(float)dp * 0.57564627324851142f);
            float sn, cs;
            sincosf((float)pos * freq, &sn, &cs);
            v[j] = (short)f2bf(bf2f((unsigned short)x1v[j]) * cs -
                               bf2f((unsigned short)x2v[j]) * sn);
        }
    } else {                     // x2 side: out = x1*sin + x2*cos
        s16x8 x1v = *(const s16x8*)(kb + d0 - 16);
        s16x8 x2v = *(const s16x8*)(kb + d0);
        for (int j = 0; j < 8; ++j) {
            int dp = d0 - 16 + j;
            float freq = expf(-(float)dp * 0.57564627324851142f);
            float sn, cs;
            sincosf((float)pos * freq, &sn, &cs);
            v[j] = (short)f2bf(bf2f((unsigned short)x1v[j]) * sn +
                               bf2f((unsigned short)x2v[j]) * cs);
        }
    }
    *(s16x8*)(Kp + (((size_t)h * 64 + (pos >> 5)) * 12 + c) * 256 + (pos & 31) * 8) = v;
}

// ---------------- pack V^T tiled: qkv v-half -> Vp[h][kblk16][80][16] ----------------
__global__ __launch_bounds__(256) void pack_v_kernel(const unsigned short* __restrict__ qkv,
                                                     unsigned short* __restrict__ Vp) {
    int h  = blockIdx.x & 31;
    int g64 = blockIdx.x >> 5;           // 0..31
    int k0 = g64 * 64;
    int tid = threadIdx.x;
    for (int ci = tid; ci < 320; ci += 256) {   // (kbl 0..3) x (d 0..79)
        int d   = ci % 80;
        int kbl = ci / 80;
        unsigned short tmp[16];
        for (int j = 0; j < 16; ++j)
            tmp[j] = qkv[(size_t)(k0 + kbl * 16 + j) * 7680 + 5120 + h * 80 + d];
        unsigned short* dst = Vp + ((size_t)h * 128 + g64 * 4 + kbl) * 1280 + d * 16;
        *(s16x8*)dst       = *(const s16x8*)&tmp[0];
        *(s16x8*)(dst + 8) = *(const s16x8*)&tmp[8];
    }
}

// ---------------- flash attention v6: 8 strips/block sharing one LDS K/V stream ----------
// Block (h, j): strips {j+16k, k=0..7}. Wave w owns pair {j+16w, j+112-16w}
// (work = 2j+114 tiles, balanced). Causal prefixes nest, so one K/V pass
// [0, (j+113)*16) serves all 8 strips -> L2/L3 traffic drops 1.49GB -> 0.34GB.
// Per 32-key unit: cooperative stage of K(6KB)+V(5KB) into LDS dbuf via
// global_load_lds (11 wave-chunks of 1KB), __syncthreads (full drain = safe
// 2-phase), waves read fragments from LDS (both patterns at the 8-cy LDS floor).
__global__ __launch_bounds__(256) void flash6_kernel(const unsigned short* __restrict__ qkv,
                                                     const unsigned short* __restrict__ Kp,
                                                     const unsigned short* __restrict__ Vp,
                                                     unsigned short* __restrict__ attn) {
    __shared__ unsigned short Ks[2][3072];     // 32 keys x 96 dims (chunk-major [12][32][8])
    __shared__ unsigned short Vs[2][2560];     // 2 x [80][16] V tiles
    __shared__ unsigned short Pt[4][640];      // per-wave 16x40 P tile
    const int tid  = threadIdx.x;
    const int lane = tid & 63;
    const int wv   = tid >> 6;
    const int h  = blockIdx.x & 31;
    const int jj = blockIdx.x >> 5;            // 0..15
    const int fr = lane & 15;
    const int fg = lane >> 4;
    const float k1 = 0.11180339887498949f * LOG2E;  // (1/sqrt(80)) * log2(e)

    const int sA  = jj + 16 * wv;
    const int sB  = jj + 112 - 16 * wv;
    const int smA = sA * 16;
    const int smB = sB * 16;
    const int Ublk = (jj + 114) >> 1;          // units covering the longest strip (j+112)

    const s16x8 zs = {0, 0, 0, 0, 0, 0, 0, 0};
    s16x8 qfA[3], qfB[3];
    {
        const unsigned short* qa = qkv + (size_t)(smA + fr) * 7680 + h * 80;
        const unsigned short* qb = qkv + (size_t)(smB + fr) * 7680 + h * 80;
        for (int sd = 0; sd < 3; ++sd) {
            int d = 32 * sd + fg * 8;
            qfA[sd] = (d < 80) ? *(const s16x8*)(qa + d) : zs;
            qfB[sd] = (d < 80) ? *(const s16x8*)(qb + d) : zs;
        }
    }

    f32x4 OA[5], OB[5];
    const f32x4 zf = {0.f, 0.f, 0.f, 0.f};
    for (int t = 0; t < 5; ++t) { OA[t] = zf; OB[t] = zf; }
    float rsA[4] = {0.f, 0.f, 0.f, 0.f};
    float rsB[4] = {0.f, 0.f, 0.f, 0.f};
    unsigned short* Pw = &Pt[wv][0];

    const unsigned short* Kh = Kp + (size_t)h * 196608;   // 64 tiles * 3072
    const unsigned short* Vh = Vp + (size_t)h * 163840;   // 128 blk * 1280

    // chunk q (0..10): q<6 -> K 1KB chunk q; else V 1KB chunk q-6. Wave w: {w, w+4, w+8}.
#define STG1(q, b, uu) { \
    if ((q) < 6) async_copy16(Kh + (size_t)(uu) * 3072 + (q) * 512 + lane * 8, &Ks[b][(q) * 512]); \
    else         async_copy16(Vh + (size_t)(uu) * 2560 + ((q) - 6) * 512 + lane * 8, &Vs[b][((q) - 6) * 512]); }
#define STAGEU(b, uu) { STG1(wv, b, uu); STG1(wv + 4, b, uu); if (wv < 3) STG1(wv + 8, b, uu); }

#define FSTEP6(QF, OO, RS, SM16, K0, BUF) { \
    s16x8 kb[2][3]; \
    _Pragma("unroll") \
    for (int g = 0; g < 2; ++g) \
        _Pragma("unroll") \
        for (int sd = 0; sd < 3; ++sd) \
            kb[g][sd] = *(const s16x8*)&Ks[BUF][(fg + sd * 4) * 256 + (g * 16 + fr) * 8]; \
    s16x8 vb[5]; \
    _Pragma("unroll") \
    for (int t = 0; t < 5; ++t) \
        vb[t] = *(const s16x8*)&Vs[BUF][(fg >> 1) * 1280 + t * 256 + fr * 16 + (fg & 1) * 8]; \
    f32x4 sa[2] = {zf, zf}; \
    __builtin_amdgcn_s_setprio(1); \
    _Pragma("unroll") \
    for (int g = 0; g < 2; ++g) \
        _Pragma("unroll") \
        for (int sd = 0; sd < 3; ++sd) \
            sa[g] = __builtin_amdgcn_mfma_f32_16x16x32_bf16(QF[sd], kb[g][sd], sa[g], 0, 0, 0); \
    __builtin_amdgcn_s_setprio(0); \
    if ((K0) + 32 > (SM16)) { \
        _Pragma("unroll") \
        for (int g = 0; g < 2; ++g) \
            _Pragma("unroll") \
            for (int r = 0; r < 4; ++r) { \
                int key  = (K0) + g * 16 + fr; \
                int qrow = (SM16) + fg * 4 + r; \
                if (key > qrow) sa[g][r] = -1e30f; \
            } \
    } \
    float pr[2][4]; \
    _Pragma("unroll") \
    for (int g = 0; g < 2; ++g) \
        _Pragma("unroll") \
        for (int r = 0; r < 4; ++r) \
            pr[g][r] = __builtin_amdgcn_exp2f(sa[g][r] * k1); \
    _Pragma("unroll") \
    for (int r = 0; r < 4; ++r) RS[r] += pr[0][r] + pr[1][r]; \
    _Pragma("unroll") \
    for (int g = 0; g < 2; ++g) \
        _Pragma("unroll") \
        for (int r = 0; r < 4; ++r) \
            Pw[(fg * 4 + r) * 40 + g * 16 + fr] = \
                (unsigned short)(__float_as_uint(pr[g][r]) >> 16); \
    s16x8 pa = *(const s16x8*)(Pw + fr * 40 + fg * 8); \
    __builtin_amdgcn_s_setprio(1); \
    _Pragma("unroll") \
    for (int t = 0; t < 5; ++t) \
        OO[t] = __builtin_amdgcn_mfma_f32_16x16x32_bf16(pa, vb[t], OO[t], 0, 0, 0); \
    __builtin_amdgcn_s_setprio(0); }

    STAGEU(0, 0);
    __syncthreads();          // full drain: unit-0 tiles resident
    int buf = 0;
    for (int u = 0; u < Ublk; ++u) {
        if (u + 1 < Ublk) STAGEU(buf ^ 1, u + 1);   // async issue; drained by the syncthreads below
        const int k0 = u * 32;
        if (2 * u <= sA) FSTEP6(qfA, OA, rsA, smA, k0, buf);
        if (2 * u <= sB) FSTEP6(qfB, OB, rsB, smB, k0, buf);
        __syncthreads();      // drains vmcnt (stage done) + lgkm (reads done) before overwrite
        buf ^= 1;
    }
#undef STG1
#undef STAGEU
#undef FSTEP6

    // epilogue: per strip, reduce row-sums over the 16 fr lanes and write normalized O
#define FIN6(RS, OO, SM16) { \
    _Pragma("unroll") \
    for (int r = 0; r < 4; ++r) { \
        float v = RS[r]; \
        v += __shfl_xor(v, 1); \
        v += __shfl_xor(v, 2); \
        v += __shfl_xor(v, 4); \
        v += __shfl_xor(v, 8); \
        RS[r] = v; \
    } \
    _Pragma("unroll") \
    for (int r = 0; r < 4; ++r) { \
        float rl = 1.0f / RS[r]; \
        int row = (SM16) + fg * 4 + r; \
        _Pragma("unroll") \
        for (int t = 0; t < 5; ++t) \
            attn[(size_t)row * 2560 + h * 80 + t * 16 + fr] = f2bf(OO[t][r] * rl); \
    } }
    FIN6(rsA, OA, smA);
    FIN6(rsB, OB, smB);
#undef FIN6
}

extern "C" void kernel_launch(void* const* d_in, const int* in_sizes, int n_in,
                              void* d_out, int out_size, void* d_ws, size_t ws_size,
                              hipStream_t stream) {
    const float* x    = (const float*)d_in[0];
    const float* wqkv = (const float*)d_in[1];
    const float* bqkv = (const float*)d_in[2];
    const float* outw = (const float*)d_in[3];
    const float* outb = (const float*)d_in[4];

    unsigned short* xb    = (unsigned short*)d_ws;                  // 2048*2560
    unsigned short* wqkvb = xb + (size_t)2048 * 2560;               // 7680*2560 (dead after gemm1)
    unsigned short* Kp    = wqkvb;                                  // 32*64*12*32*8 (aliases wqkvb)
    unsigned short* Vp    = wqkvb + (size_t)32 * 2048 * 96;         // 32*128*1280  (aliases wqkvb)
    unsigned short* outwb = wqkvb + (size_t)7680 * 2560;            // 2560*2560
    unsigned short* qkvb  = outwb + (size_t)2560 * 2560;            // 2048*7680
    unsigned short* attnb = qkvb  + (size_t)2048 * 7680;            // 2048*2560
    float* out = (float*)d_out;

    cast_bf16_kernel<<<2048 * 2560 / 4 / 256, 256, 0, stream>>>(x, xb, 2048 * 2560 / 4);
    cast_bf16_kernel<<<7680 * 2560 / 4 / 256, 256, 0, stream>>>(wqkv, wqkvb, 7680 * 2560 / 4);
    cast_bf16_kernel<<<2560 * 2560 / 4 / 256, 256, 0, stream>>>(outw, outwb, 2560 * 2560 / 4);

    // qkv projection: 256x256 v3 pipeline, 240 blocks, XCD-chunked panel-sharing map
    gemm256_bt<<<240, 512, 0, stream>>>(xb, wqkvb, bqkv, qkvb, 2048, 7680, 2560);

    rope_q_kernel<<<2048 * 64 / 256, 256, 0, stream>>>(qkvb);
    rope_pack_k_kernel<<<2048 * 384 / 256, 256, 0, stream>>>(qkvb, Kp);
    pack_v_kernel<<<32 * 32, 256, 0, stream>>>(qkvb, Vp);

    // 512 blocks = 32 heads x 16 strip-octets; K/V shared across 128 q-rows per block
    flash6_kernel<<<512, 256, 0, stream>>>(qkvb, Kp, Vp, attnb);

    gemm_bt<false><<<dim3(2560 / 128, 2048 / 128), 256, 0, stream>>>(
        attnb, outwb, outb, (void*)out, 2048, 2560, 2560);
}

// Round 7
// 411.170 us; speedup vs baseline: 1.0871x; 1.0118x over previous
//
#include <hip/hip_runtime.h>
#include <cstdint>
#include <cmath>

typedef __attribute__((ext_vector_type(4))) float f32x4;
typedef __attribute__((ext_vector_type(8))) short s16x8;

#define LOG2E 1.4426950408889634f

__device__ __forceinline__ unsigned short f2bf(float f) {
    unsigned int u = __float_as_uint(f);
    u += 0x7FFFu + ((u >> 16) & 1u);   // round-to-nearest-even
    return (unsigned short)(u >> 16);
}
__device__ __forceinline__ float bf2f(unsigned short s) {
    return __uint_as_float(((unsigned int)s) << 16);
}

// async global->LDS, 16B per lane. LDS dest is wave-uniform base + lane*16.
__device__ __forceinline__ void async_copy16(const void* g, void* l) {
    __builtin_amdgcn_global_load_lds(
        (const __attribute__((address_space(1))) unsigned int*)(uintptr_t)g,
        (__attribute__((address_space(3))) unsigned int*)(uintptr_t)l,
        16, 0, 0);
}

// ---------------- fp32 -> bf16 cast ----------------
__global__ __launch_bounds__(256) void cast_bf16_kernel(const float* __restrict__ in,
                                                        unsigned short* __restrict__ out,
                                                        int n4) {
    int i = blockIdx.x * 256 + threadIdx.x;
    if (i < n4) {
        float4 v = ((const float4*)in)[i];
        ushort4 o;
        o.x = f2bf(v.x); o.y = f2bf(v.y); o.z = f2bf(v.z); o.w = f2bf(v.w);
        ((ushort4*)out)[i] = o;
    }
}

// ---------------- GEMM (128x128 2-phase) — kept for the output projection ----------------
template <bool BF16_OUT>
__global__ __launch_bounds__(256) void gemm_bt(const unsigned short* __restrict__ A,
                                               const unsigned short* __restrict__ B,
                                               const float* __restrict__ bias,
                                               void* __restrict__ Cout,
                                               int M, int N, int K) {
    __shared__ unsigned short As[128 * 64];   // 16 KB
    __shared__ unsigned short Bs[128 * 64];   // 16 KB
    const int tid  = threadIdx.x;
    const int lane = tid & 63;
    const int wv   = tid >> 6;
    const int m0 = blockIdx.y * 128;
    const int n0 = blockIdx.x * 128;
    const int w_row = (wv >> 1) * 64;
    const int w_col = (wv & 1) * 64;
    const int fr = lane & 15;
    const int fg = lane >> 4;
    const int srow = lane >> 3;
    const int scol = ((lane & 7) ^ srow) * 8;
    const int rofs0 = ((fg ^ (fr & 7))) * 8;
    const int rofs1 = rofs0 ^ 32;

    f32x4 acc[4][4];
    const f32x4 zf = {0.f, 0.f, 0.f, 0.f};
    for (int r = 0; r < 4; ++r)
        for (int c = 0; c < 4; ++c) acc[r][c] = zf;

    const unsigned short* gA = A + (size_t)(m0 + wv * 32 + srow) * K + scol;
    const unsigned short* gB = B + (size_t)(n0 + wv * 32 + srow) * K + scol;

    for (int k0 = 0; k0 < K; k0 += 64) {
        for (int i = 0; i < 4; ++i)
            async_copy16(gA + (size_t)i * 8 * K + k0, &As[(wv * 32 + i * 8) * 64]);
        for (int i = 0; i < 4; ++i)
            async_copy16(gB + (size_t)i * 8 * K + k0, &Bs[(wv * 32 + i * 8) * 64]);
        __syncthreads();
        {
            s16x8 af[4], bf[4];
            for (int r = 0; r < 4; ++r)
                af[r] = *(const s16x8*)&As[(w_row + r * 16 + fr) * 64 + rofs0];
            for (int c = 0; c < 4; ++c)
                bf[c] = *(const s16x8*)&Bs[(w_col + c * 16 + fr) * 64 + rofs0];
            for (int r = 0; r < 4; ++r)
                for (int c = 0; c < 4; ++c)
                    acc[r][c] = __builtin_amdgcn_mfma_f32_16x16x32_bf16(af[r], bf[c], acc[r][c], 0, 0, 0);
        }
        {
            s16x8 af[4], bf[4];
            for (int r = 0; r < 4; ++r)
                af[r] = *(const s16x8*)&As[(w_row + r * 16 + fr) * 64 + rofs1];
            for (int c = 0; c < 4; ++c)
                bf[c] = *(const s16x8*)&Bs[(w_col + c * 16 + fr) * 64 + rofs1];
            for (int r = 0; r < 4; ++r)
                for (int c = 0; c < 4; ++c)
                    acc[r][c] = __builtin_amdgcn_mfma_f32_16x16x32_bf16(af[r], bf[c], acc[r][c], 0, 0, 0);
        }
        __syncthreads();
    }

    const int rb = (lane >> 4) * 4;
    for (int c = 0; c < 4; ++c) {
        int col = n0 + w_col + c * 16 + fr;
        float bv = bias[col];
        for (int r = 0; r < 4; ++r) {
            int row = m0 + w_row + r * 16 + rb;
            for (int q = 0; q < 4; ++q) {
                float v = acc[r][c][q] + bv;
                if constexpr (BF16_OUT)
                    ((unsigned short*)Cout)[(size_t)(row + q) * N + col] = f2bf(v);
                else
                    ((float*)Cout)[(size_t)(row + q) * N + col] = v;
            }
        }
    }
}

// ---------------- GEMM 256x256, BK=64, 8 waves — v3: decoupled read/MFMA pipeline ----------
// Per tile t (buf b), quadrant order Q00,Q01,Q11,Q10. Each phase:
//   {setprio(1) MFMA(regs read >=1 phase ago) setprio(0); VMW(6); ds_reads(next); stage; BAR}
// Reads: P1: B1(t) [use P2]; P2: A1(t) [use P3]; P3: none; P4: A0,B0(t+1) from buf^1 [use P1'].
// Staging: P1: AS1(t+1)->buf^1; P2: AS0(t+2); P3: BS0(t+2); P4: BS1(t+2).
// Uniform VMW(6): 6-8 loads in flight; each phase's drain covers the read 1+ phase later.

#define BAR()   __builtin_amdgcn_s_barrier()
#define VMW(N)  asm volatile("s_waitcnt vmcnt(" #N ")" ::: "memory")

#define STAGE2(gXb, XsBuf, rb, kk) \
    async_copy16(gXb + (size_t)(rb) * K + (kk), (void*)&XsBuf[(rb) * 64])

#define ST_AS0(b, kk) { STAGE2(gAb, As[b], rbA_0, kk);      STAGE2(gAb, As[b], rbA_1, kk); }
#define ST_AS1(b, kk) { STAGE2(gAb, As[b], rbA_0 + 64, kk); STAGE2(gAb, As[b], rbA_1 + 64, kk); }
#define ST_BS0(b, kk) { STAGE2(gBb, Bs[b], rbB_0, kk);      STAGE2(gBb, Bs[b], rbB_1, kk); }
#define ST_BS1(b, kk) { STAGE2(gBb, Bs[b], rbB_0 + 32, kk); STAGE2(gBb, Bs[b], rbB_1 + 32, kk); }

#define READ_A(b, mh) \
    _Pragma("unroll") \
    for (int mm_ = 0; mm_ < 4; ++mm_) { \
        const unsigned short* ap_ = &As[b][(wr * 128 + (mh) * 64 + mm_ * 16 + fr) * 64]; \
        Ar[mm_][0] = *(const s16x8*)(ap_ + rofs0); \
        Ar[mm_][1] = *(const s16x8*)(ap_ + rofs1); \
    }

#define READ_B(b, nh, Brg) \
    _Pragma("unroll") \
    for (int nn_ = 0; nn_ < 2; ++nn_) { \
        const unsigned short* bp_ = &Bs[b][(wc * 64 + (nh) * 32 + nn_ * 16 + fr) * 64]; \
        Brg[nn_][0] = *(const s16x8*)(bp_ + rofs0); \
        Brg[nn_][1] = *(const s16x8*)(bp_ + rofs1); \
    }

#define MFMA_Q(mh, nh, Brg) \
    _Pragma("unroll") \
    for (int mm_ = 0; mm_ < 4; ++mm_) { \
        _Pragma("unroll") \
        for (int nn_ = 0; nn_ < 2; ++nn_) { \
            acc[(mh) * 4 + mm_][(nh) * 2 + nn_] = __builtin_amdgcn_mfma_f32_16x16x32_bf16( \
                Ar[mm_][0], Brg[nn_][0], acc[(mh) * 4 + mm_][(nh) * 2 + nn_], 0, 0, 0); \
            acc[(mh) * 4 + mm_][(nh) * 2 + nn_] = __builtin_amdgcn_mfma_f32_16x16x32_bf16( \
                Ar[mm_][1], Brg[nn_][1], acc[(mh) * 4 + mm_][(nh) * 2 + nn_], 0, 0, 0); \
        } \
    }

#define GROUP(b, t) { \
    int x1_ = (t) + 1; if (x1_ >= ktiles) x1_ -= ktiles; \
    int x2_ = (t) + 2; if (x2_ >= ktiles) x2_ -= ktiles; \
    const int kn1 = x1_ << 6; \
    const int kn2 = x2_ << 6; \
    /* P1: Q00 (A0 x B0, regs from P4(t-1)); read B1(t); stage AS1(t+1) */ \
    __builtin_amdgcn_s_setprio(1); MFMA_Q(0, 0, Br0); __builtin_amdgcn_s_setprio(0); \
    VMW(6); \
    READ_B(b, 1, Br1); \
    ST_AS1((b) ^ 1, kn1); \
    BAR(); \
    /* P2: Q01 (A0 x B1); read A1(t) (frees A0 after MFMA); stage AS0(t+2) */ \
    __builtin_amdgcn_s_setprio(1); MFMA_Q(0, 1, Br1); __builtin_amdgcn_s_setprio(0); \
    VMW(6); \
    READ_A(b, 1); \
    ST_AS0(b, kn2); \
    BAR(); \
    /* P3: Q11 (A1 x B1); stage BS0(t+2) */ \
    __builtin_amdgcn_s_setprio(1); MFMA_Q(1, 1, Br1); __builtin_amdgcn_s_setprio(0); \
    VMW(6); \
    ST_BS0(b, kn2); \
    BAR(); \
    /* P4: Q10 (A1 x B0); read A0,B0 of tile t+1 from buf^1; stage BS1(t+2) */ \
    __builtin_amdgcn_s_setprio(1); MFMA_Q(1, 0, Br0); __builtin_amdgcn_s_setprio(0); \
    VMW(6); \
    READ_A((b) ^ 1, 0); \
    READ_B((b) ^ 1, 0, Br0); \
    ST_BS1(b, kn2); \
    BAR(); \
}

__global__ __launch_bounds__(512, 2) void gemm256_bt(const unsigned short* __restrict__ A,
                                                     const unsigned short* __restrict__ B,
                                                     const float* __restrict__ bias,
                                                     unsigned short* __restrict__ C,
                                                     int M, int N, int K) {
    __shared__ unsigned short As[2][256 * 64];   // 64 KB
    __shared__ unsigned short Bs[2][256 * 64];   // 64 KB
    const int tid  = threadIdx.x;
    const int lane = tid & 63;
    const int wv   = tid >> 6;      // 0..7
    const int wr   = wv >> 2;       // 0..1 (M-half)
    const int wc   = wv & 3;        // 0..3 (N-quarter)
    // XCD-aware chunked mapping (round-robin dispatch: xcd = bid&7).
    // Each XCD: 2 A-strips x 15 B-panels; each B-panel shared by 2 co-XCD blocks.
    const int j     = blockIdx.x & 7;
    const int local = blockIdx.x >> 3;
    const int strip = 2 * (j & 3) + (local & 1);
    const int panel = (j >> 2) * 15 + (local >> 1);
    const int m0 = strip * 256;
    const int n0 = panel * 256;
    const int fr = lane & 15;
    const int fg = lane >> 4;
    const int rofs0 = (fg ^ (fr & 7)) * 8;
    const int rofs1 = rofs0 ^ 32;
    // staging: lane covers row (lane>>3), fetches global chunk (lane&7)^((lane>>3)&7)
    const int rlane = lane >> 3;
    const int swzc  = ((lane & 7) ^ (rlane & 7)) * 8;
    const int idx0 = wv * 2, idx1 = wv * 2 + 1;
    const int rbA_0 = idx0 * 8 + ((idx0 >= 8) ? 64 : 0);  // A-S0 row bases
    const int rbA_1 = idx1 * 8 + ((idx1 >= 8) ? 64 : 0);
    const int rbB_0 = (idx0 >> 2) * 64 + (idx0 & 3) * 8;  // B-S0 row bases
    const int rbB_1 = (idx1 >> 2) * 64 + (idx1 & 3) * 8;
    const int ktiles = K >> 6;      // 40

    const unsigned short* gAb = A + (size_t)(m0 + rlane) * K + swzc;
    const unsigned short* gBb = B + (size_t)(n0 + rlane) * K + swzc;

    f32x4 acc[8][4];
    const f32x4 zf = {0.f, 0.f, 0.f, 0.f};
#pragma unroll
    for (int i = 0; i < 8; ++i)
#pragma unroll
        for (int jj = 0; jj < 4; ++jj) acc[i][jj] = zf;

    s16x8 Ar[4][2], Br0[2][2], Br1[2][2];

    // prologue: tile0 complete + tile1 {AS0, BS0, BS1} (AS1(1) comes in P1 of GROUP 0);
    // drain tile0 (VMW(6) leaves tile1's 6 in flight); pre-read A0(t0), B0(t0).
    ST_AS0(0, 0); ST_AS1(0, 0); ST_BS0(0, 0); ST_BS1(0, 0);
    ST_AS0(1, 64); ST_BS0(1, 64); ST_BS1(1, 64);
    VMW(6);
    BAR();
    READ_A(0, 0);
    READ_B(0, 0, Br0);

    const int nit = ktiles >> 1;
    for (int it = 0; it < nit; ++it) {
        GROUP(0, it * 2);
        GROUP(1, it * 2 + 1);
    }

    // epilogue: C/D layout col=lane&15, row=(lane>>4)*4+reg
    const int rb = (lane >> 4) * 4;
#pragma unroll
    for (int nn = 0; nn < 4; ++nn) {
        int col = n0 + wc * 64 + nn * 16 + fr;
        float bv = bias[col];
#pragma unroll
        for (int mm = 0; mm < 8; ++mm) {
            int row = m0 + wr * 128 + mm * 16 + rb;
#pragma unroll
            for (int q = 0; q < 4; ++q) {
                float v = acc[mm][nn][q] + bv;
                C[(size_t)(row + q) * N + col] = f2bf(v);
            }
        }
    }
}

// ---------------- RoPE in-place on q-half only (k handled in rope_pack_k) ----------------
__global__ __launch_bounds__(256) void rope_q_kernel(unsigned short* __restrict__ qkv) {
    int g = blockIdx.x * 256 + threadIdx.x;  // 2048*32*2 items
    int c = g & 1;            // half-chunk: pairs d0..d0+7
    int h = (g >> 1) & 31;
    int p = g >> 6;
    size_t base = (size_t)p * 7680 + h * 80 + c * 8;
    s16x8 x1v = *(const s16x8*)(qkv + base);
    s16x8 x2v = *(const s16x8*)(qkv + base + 16);
    s16x8 o1, o2;
    for (int j = 0; j < 8; ++j) {
        int dp = c * 8 + j;
        float freq = expf(-(float)dp * 0.57564627324851142f);  // ln(10000)/16
        float sn, cs;
        sincosf((float)p * freq, &sn, &cs);
        float x1 = bf2f((unsigned short)x1v[j]);
        float x2 = bf2f((unsigned short)x2v[j]);
        o1[j] = (short)f2bf(x1 * cs - x2 * sn);
        o2[j] = (short)f2bf(x1 * sn + x2 * cs);
    }
    *(s16x8*)(qkv + base)      = o1;
    *(s16x8*)(qkv + base + 16) = o2;
}

// ---------------- fused k-RoPE + pack: qkv k-half -> Kp[h][u32][12][32][8] ----------------
// Chunk-major per 32-key tile so flash can (a) stage linearly with global_load_lds and
// (b) read MFMA fragments from LDS at the bank-throughput floor.
__global__ __launch_bounds__(256) void rope_pack_k_kernel(const unsigned short* __restrict__ qkv,
                                                          unsigned short* __restrict__ Kp) {
    int g = blockIdx.x * 256 + threadIdx.x;  // 2048*32*12
    int c   = g % 12;
    int h   = (g / 12) & 31;
    int pos = g / 384;
    int d0 = c * 8;
    const unsigned short* kb = qkv + (size_t)pos * 7680 + 2560 + h * 80;
    s16x8 v = {0, 0, 0, 0, 0, 0, 0, 0};
    if (c >= 4) {
        if (d0 < 80) v = *(const s16x8*)(kb + d0);
    } else if (c < 2) {          // x1 side: out = x1*cos - x2*sin
        s16x8 x1v = *(const s16x8*)(kb + d0);
        s16x8 x2v = *(const s16x8*)(kb + d0 + 16);
        for (int j = 0; j < 8; ++j) {
            int dp = d0 + j;
            float freq = expf(-(float)dp * 0.57564627324851142f);
            float sn, cs;
            sincosf((float)pos * freq, &sn, &cs);
            v[j] = (short)f2bf(bf2f((unsigned short)x1v[j]) * cs -
                               bf2f((unsigned short)x2v[j]) * sn);
        }
    } else {                     // x2 side: out = x1*sin + x2*cos
        s16x8 x1v = *(const s16x8*)(kb + d0 - 16);
        s16x8 x2v = *(const s16x8*)(kb + d0);
        for (int j = 0; j < 8; ++j) {
            int dp = d0 - 16 + j;
            float freq = expf(-(float)dp * 0.57564627324851142f);
            float sn, cs;
            sincosf((float)pos * freq, &sn, &cs);
            v[j] = (short)f2bf(bf2f((unsigned short)x1v[j]) * sn +
                               bf2f((unsigned short)x2v[j]) * cs);
        }
    }
    *(s16x8*)(Kp + (((size_t)h * 64 + (pos >> 5)) * 12 + c) * 256 + (pos & 31) * 8) = v;
}

// ---------------- pack V^T tiled: qkv v-half -> Vp[h][kblk16][80][16] ----------------
__global__ __launch_bounds__(256) void pack_v_kernel(const unsigned short* __restrict__ qkv,
                                                     unsigned short* __restrict__ Vp) {
    int h  = blockIdx.x & 31;
    int g64 = blockIdx.x >> 5;           // 0..31
    int k0 = g64 * 64;
    int tid = threadIdx.x;
    for (int ci = tid; ci < 320; ci += 256) {   // (kbl 0..3) x (d 0..79)
        int d   = ci % 80;
        int kbl = ci / 80;
        unsigned short tmp[16];
        for (int j = 0; j < 16; ++j)
            tmp[j] = qkv[(size_t)(k0 + kbl * 16 + j) * 7680 + 5120 + h * 80 + d];
        unsigned short* dst = Vp + ((size_t)h * 128 + g64 * 4 + kbl) * 1280 + d * 16;
        *(s16x8*)dst       = *(const s16x8*)&tmp[0];
        *(s16x8*)(dst + 8) = *(const s16x8*)&tmp[8];
    }
}

// ---------------- flash attention v7: shared-K/V hoist + interleaved strip pair ----------
// v6 structure (8 strips/block, wave pair {jj+16w, jj+112-16w}, LDS K/V dbuf) with the
// DS-pipe fix: K/V fragments are read from LDS ONCE per 32-key unit and reused by both
// strips (the unit's K-tile is identical for them), and the two strips' QK/softmax/PV
// chains are interleaved in one straight-line body so MFMA of one overlaps VALU/lgkm of
// the other. Single P tile per wave stays correct: same-wave DS ops execute in order
// (P_A write -> pa_A read -> P_B write -> pa_B read).
__global__ __launch_bounds__(256) void flash6_kernel(const unsigned short* __restrict__ qkv,
                                                     const unsigned short* __restrict__ Kp,
                                                     const unsigned short* __restrict__ Vp,
                                                     unsigned short* __restrict__ attn) {
    __shared__ unsigned short Ks[2][3072];     // 32 keys x 96 dims (chunk-major [12][32][8])
    __shared__ unsigned short Vs[2][2560];     // 2 x [80][16] V tiles
    __shared__ unsigned short Pt[4][640];      // per-wave 16x40 P tile
    const int tid  = threadIdx.x;
    const int lane = tid & 63;
    const int wv   = tid >> 6;
    const int h  = blockIdx.x & 31;
    const int jj = blockIdx.x >> 5;            // 0..15
    const int fr = lane & 15;
    const int fg = lane >> 4;
    const float k1 = 0.11180339887498949f * LOG2E;  // (1/sqrt(80)) * log2(e)

    const int sA  = jj + 16 * wv;
    const int sB  = jj + 112 - 16 * wv;
    const int smA = sA * 16;
    const int smB = sB * 16;
    const int Ublk = (jj + 114) >> 1;          // units covering the longest strip (j+112)

    const s16x8 zs = {0, 0, 0, 0, 0, 0, 0, 0};
    s16x8 qfA[3], qfB[3];
    {
        const unsigned short* qa = qkv + (size_t)(smA + fr) * 7680 + h * 80;
        const unsigned short* qb = qkv + (size_t)(smB + fr) * 7680 + h * 80;
        for (int sd = 0; sd < 3; ++sd) {
            int d = 32 * sd + fg * 8;
            qfA[sd] = (d < 80) ? *(const s16x8*)(qa + d) : zs;
            qfB[sd] = (d < 80) ? *(const s16x8*)(qb + d) : zs;
        }
    }

    f32x4 OA[5], OB[5];
    const f32x4 zf = {0.f, 0.f, 0.f, 0.f};
    for (int t = 0; t < 5; ++t) { OA[t] = zf; OB[t] = zf; }
    float rsA[4] = {0.f, 0.f, 0.f, 0.f};
    float rsB[4] = {0.f, 0.f, 0.f, 0.f};
    unsigned short* Pw = &Pt[wv][0];

    const unsigned short* Kh = Kp + (size_t)h * 196608;   // 64 tiles * 3072
    const unsigned short* Vh = Vp + (size_t)h * 163840;   // 128 blk * 1280

    // chunk q (0..10): q<6 -> K 1KB chunk q; else V 1KB chunk q-6. Wave w: {w, w+4, w+8}.
#define STG1(q, b, uu) { \
    if ((q) < 6) async_copy16(Kh + (size_t)(uu) * 3072 + (q) * 512 + lane * 8, &Ks[b][(q) * 512]); \
    else         async_copy16(Vh + (size_t)(uu) * 2560 + ((q) - 6) * 512 + lane * 8, &Vs[b][((q) - 6) * 512]); }
#define STAGEU(b, uu) { STG1(wv, b, uu); STG1(wv + 4, b, uu); if (wv < 3) STG1(wv + 8, b, uu); }

    // softmax section for one strip: mask, exp, rowsum, P write, pa read
#define SMX(SA, RS, SM16, K0, PA) { \
    if ((K0) + 32 > (SM16)) { \
        _Pragma("unroll") \
        for (int g = 0; g < 2; ++g) \
            _Pragma("unroll") \
            for (int r = 0; r < 4; ++r) { \
                int key  = (K0) + g * 16 + fr; \
                int qrow = (SM16) + fg * 4 + r; \
                if (key > qrow) SA[g][r] = -1e30f; \
            } \
    } \
    float pr[2][4]; \
    _Pragma("unroll") \
    for (int g = 0; g < 2; ++g) \
        _Pragma("unroll") \
        for (int r = 0; r < 4; ++r) \
            pr[g][r] = __builtin_amdgcn_exp2f(SA[g][r] * k1); \
    _Pragma("unroll") \
    for (int r = 0; r < 4; ++r) RS[r] += pr[0][r] + pr[1][r]; \
    _Pragma("unroll") \
    for (int g = 0; g < 2; ++g) \
        _Pragma("unroll") \
        for (int r = 0; r < 4; ++r) \
            Pw[(fg * 4 + r) * 40 + g * 16 + fr] = \
                (unsigned short)(__float_as_uint(pr[g][r]) >> 16); \
    PA = *(const s16x8*)(Pw + fr * 40 + fg * 8); }

    STAGEU(0, 0);
    __syncthreads();          // full drain: unit-0 tiles resident
    int buf = 0;
    for (int u = 0; u < Ublk; ++u) {
        if (u + 1 < Ublk) STAGEU(buf ^ 1, u + 1);   // async issue; drained by the syncthreads below
        const int k0 = u * 32;
        const bool actA = (2 * u <= sA);            // sB >= sA: actB covers "any active"
        const bool actB = (2 * u <= sB);
        if (actB) {
            // hoisted K/V fragment reads — shared by both strips (same unit tile)
            s16x8 kb[2][3];
#pragma unroll
            for (int g = 0; g < 2; ++g)
#pragma unroll
                for (int sd = 0; sd < 3; ++sd)
                    kb[g][sd] = *(const s16x8*)&Ks[buf][(fg + sd * 4) * 256 + (g * 16 + fr) * 8];
            s16x8 vb[5];
#pragma unroll
            for (int t = 0; t < 5; ++t)
                vb[t] = *(const s16x8*)&Vs[buf][(fg >> 1) * 1280 + t * 256 + fr * 16 + (fg & 1) * 8];

            f32x4 saA[2] = {zf, zf};
            f32x4 saB[2] = {zf, zf};
            __builtin_amdgcn_s_setprio(1);
            if (actA) {
#pragma unroll
                for (int g = 0; g < 2; ++g)
#pragma unroll
                    for (int sd = 0; sd < 3; ++sd)
                        saA[g] = __builtin_amdgcn_mfma_f32_16x16x32_bf16(qfA[sd], kb[g][sd], saA[g], 0, 0, 0);
            }
#pragma unroll
            for (int g = 0; g < 2; ++g)
#pragma unroll
                for (int sd = 0; sd < 3; ++sd)
                    saB[g] = __builtin_amdgcn_mfma_f32_16x16x32_bf16(qfB[sd], kb[g][sd], saB[g], 0, 0, 0);
            __builtin_amdgcn_s_setprio(0);

            s16x8 paA, paB;
            if (actA) SMX(saA, rsA, smA, k0, paA);
            SMX(saB, rsB, smB, k0, paB);

            __builtin_amdgcn_s_setprio(1);
            if (actA) {
#pragma unroll
                for (int t = 0; t < 5; ++t)
                    OA[t] = __builtin_amdgcn_mfma_f32_16x16x32_bf16(paA, vb[t], OA[t], 0, 0, 0);
            }
#pragma unroll
            for (int t = 0; t < 5; ++t)
                OB[t] = __builtin_amdgcn_mfma_f32_16x16x32_bf16(paB, vb[t], OB[t], 0, 0, 0);
            __builtin_amdgcn_s_setprio(0);
        }
        __syncthreads();      // drains vmcnt (stage done) + lgkm (reads done) before overwrite
        buf ^= 1;
    }
#undef STG1
#undef STAGEU
#undef SMX

    // epilogue: per strip, reduce row-sums over the 16 fr lanes and write normalized O
#define FIN6(RS, OO, SM16) { \
    _Pragma("unroll") \
    for (int r = 0; r < 4; ++r) { \
        float v = RS[r]; \
        v += __shfl_xor(v, 1); \
        v += __shfl_xor(v, 2); \
        v += __shfl_xor(v, 4); \
        v += __shfl_xor(v, 8); \
        RS[r] = v; \
    } \
    _Pragma("unroll") \
    for (int r = 0; r < 4; ++r) { \
        float rl = 1.0f / RS[r]; \
        int row = (SM16) + fg * 4 + r; \
        _Pragma("unroll") \
        for (int t = 0; t < 5; ++t) \
            attn[(size_t)row * 2560 + h * 80 + t * 16 + fr] = f2bf(OO[t][r] * rl); \
    } }
    FIN6(rsA, OA, smA);
    FIN6(rsB, OB, smB);
#undef FIN6
}

extern "C" void kernel_launch(void* const* d_in, const int* in_sizes, int n_in,
                              void* d_out, int out_size, void* d_ws, size_t ws_size,
                              hipStream_t stream) {
    const float* x    = (const float*)d_in[0];
    const float* wqkv = (const float*)d_in[1];
    const float* bqkv = (const float*)d_in[2];
    const float* outw = (const float*)d_in[3];
    const float* outb = (const float*)d_in[4];

    unsigned short* xb    = (unsigned short*)d_ws;                  // 2048*2560
    unsigned short* wqkvb = xb + (size_t)2048 * 2560;               // 7680*2560 (dead after gemm1)
    unsigned short* Kp    = wqkvb;                                  // 32*64*12*32*8 (aliases wqkvb)
    unsigned short* Vp    = wqkvb + (size_t)32 * 2048 * 96;         // 32*128*1280  (aliases wqkvb)
    unsigned short* outwb = wqkvb + (size_t)7680 * 2560;            // 2560*2560
    unsigned short* qkvb  = outwb + (size_t)2560 * 2560;            // 2048*7680
    unsigned short* attnb = qkvb  + (size_t)2048 * 7680;            // 2048*2560
    float* out = (float*)d_out;

    cast_bf16_kernel<<<2048 * 2560 / 4 / 256, 256, 0, stream>>>(x, xb, 2048 * 2560 / 4);
    cast_bf16_kernel<<<7680 * 2560 / 4 / 256, 256, 0, stream>>>(wqkv, wqkvb, 7680 * 2560 / 4);
    cast_bf16_kernel<<<2560 * 2560 / 4 / 256, 256, 0, stream>>>(outw, outwb, 2560 * 2560 / 4);

    // qkv projection: 256x256 v3 pipeline, 240 blocks, XCD-chunked panel-sharing map
    gemm256_bt<<<240, 512, 0, stream>>>(xb, wqkvb, bqkv, qkvb, 2048, 7680, 2560);

    rope_q_kernel<<<2048 * 64 / 256, 256, 0, stream>>>(qkvb);
    rope_pack_k_kernel<<<2048 * 384 / 256, 256, 0, stream>>>(qkvb, Kp);
    pack_v_kernel<<<32 * 32, 256, 0, stream>>>(qkvb, Vp);

    // 512 blocks = 32 heads x 16 strip-octets; K/V shared across 128 q-rows per block
    flash6_kernel<<<512, 256, 0, stream>>>(qkvb, Kp, Vp, attnb);

    gemm_bt<false><<<dim3(2560 / 128, 2048 / 128), 256, 0, stream>>>(
        attnb, outwb, outb, (void*)out, 2048, 2560, 2560);
}

// Round 9
// 407.425 us; speedup vs baseline: 1.0970x; 1.0092x over previous
//
#include <hip/hip_runtime.h>
#include <cstdint>
#include <cmath>

typedef __attribute__((ext_vector_type(4))) float f32x4;
typedef __attribute__((ext_vector_type(8))) short s16x8;
typedef __attribute__((ext_vector_type(4))) unsigned int u32x4;

#define LOG2E 1.4426950408889634f

__device__ __forceinline__ unsigned short f2bf(float f) {
    unsigned int u = __float_as_uint(f);
    u += 0x7FFFu + ((u >> 16) & 1u);   // round-to-nearest-even
    return (unsigned short)(u >> 16);
}
__device__ __forceinline__ float bf2f(unsigned short s) {
    return __uint_as_float(((unsigned int)s) << 16);
}

// async global->LDS, 16B per lane. LDS dest is wave-uniform base + lane*16.
__device__ __forceinline__ void async_copy16(const void* g, void* l) {
    __builtin_amdgcn_global_load_lds(
        (const __attribute__((address_space(1))) unsigned int*)(uintptr_t)g,
        (__attribute__((address_space(3))) unsigned int*)(uintptr_t)l,
        16, 0, 0);
}

// ---------------- fp32 -> bf16 cast ----------------
__global__ __launch_bounds__(256) void cast_bf16_kernel(const float* __restrict__ in,
                                                        unsigned short* __restrict__ out,
                                                        int n4) {
    int i = blockIdx.x * 256 + threadIdx.x;
    if (i < n4) {
        float4 v = ((const float4*)in)[i];
        ushort4 o;
        o.x = f2bf(v.x); o.y = f2bf(v.y); o.z = f2bf(v.z); o.w = f2bf(v.w);
        ((ushort4*)out)[i] = o;
    }
}

// ---------------- GEMM (128x128 2-phase) — kept for the output projection ----------------
template <bool BF16_OUT>
__global__ __launch_bounds__(256) void gemm_bt(const unsigned short* __restrict__ A,
                                               const unsigned short* __restrict__ B,
                                               const float* __restrict__ bias,
                                               void* __restrict__ Cout,
                                               int M, int N, int K) {
    __shared__ unsigned short As[128 * 64];   // 16 KB
    __shared__ unsigned short Bs[128 * 64];   // 16 KB
    const int tid  = threadIdx.x;
    const int lane = tid & 63;
    const int wv   = tid >> 6;
    const int m0 = blockIdx.y * 128;
    const int n0 = blockIdx.x * 128;
    const int w_row = (wv >> 1) * 64;
    const int w_col = (wv & 1) * 64;
    const int fr = lane & 15;
    const int fg = lane >> 4;
    const int srow = lane >> 3;
    const int scol = ((lane & 7) ^ srow) * 8;
    const int rofs0 = ((fg ^ (fr & 7))) * 8;
    const int rofs1 = rofs0 ^ 32;

    f32x4 acc[4][4];
    const f32x4 zf = {0.f, 0.f, 0.f, 0.f};
    for (int r = 0; r < 4; ++r)
        for (int c = 0; c < 4; ++c) acc[r][c] = zf;

    const unsigned short* gA = A + (size_t)(m0 + wv * 32 + srow) * K + scol;
    const unsigned short* gB = B + (size_t)(n0 + wv * 32 + srow) * K + scol;

    for (int k0 = 0; k0 < K; k0 += 64) {
        for (int i = 0; i < 4; ++i)
            async_copy16(gA + (size_t)i * 8 * K + k0, &As[(wv * 32 + i * 8) * 64]);
        for (int i = 0; i < 4; ++i)
            async_copy16(gB + (size_t)i * 8 * K + k0, &Bs[(wv * 32 + i * 8) * 64]);
        __syncthreads();
        {
            s16x8 af[4], bf[4];
            for (int r = 0; r < 4; ++r)
                af[r] = *(const s16x8*)&As[(w_row + r * 16 + fr) * 64 + rofs0];
            for (int c = 0; c < 4; ++c)
                bf[c] = *(const s16x8*)&Bs[(w_col + c * 16 + fr) * 64 + rofs0];
            for (int r = 0; r < 4; ++r)
                for (int c = 0; c < 4; ++c)
                    acc[r][c] = __builtin_amdgcn_mfma_f32_16x16x32_bf16(af[r], bf[c], acc[r][c], 0, 0, 0);
        }
        {
            s16x8 af[4], bf[4];
            for (int r = 0; r < 4; ++r)
                af[r] = *(const s16x8*)&As[(w_row + r * 16 + fr) * 64 + rofs1];
            for (int c = 0; c < 4; ++c)
                bf[c] = *(const s16x8*)&Bs[(w_col + c * 16 + fr) * 64 + rofs1];
            for (int r = 0; r < 4; ++r)
                for (int c = 0; c < 4; ++c)
                    acc[r][c] = __builtin_amdgcn_mfma_f32_16x16x32_bf16(af[r], bf[c], acc[r][c], 0, 0, 0);
        }
        __syncthreads();
    }

    const int rb = (lane >> 4) * 4;
    for (int c = 0; c < 4; ++c) {
        int col = n0 + w_col + c * 16 + fr;
        float bv = bias[col];
        for (int r = 0; r < 4; ++r) {
            int row = m0 + w_row + r * 16 + rb;
            for (int q = 0; q < 4; ++q) {
                float v = acc[r][c][q] + bv;
                if constexpr (BF16_OUT)
                    ((unsigned short*)Cout)[(size_t)(row + q) * N + col] = f2bf(v);
                else
                    ((float*)Cout)[(size_t)(row + q) * N + col] = v;
            }
        }
    }
}

// ---------------- GEMM 256x256, BK=64, 8 waves — v3: decoupled read/MFMA pipeline ----------
// Per tile t (buf b), quadrant order Q00,Q01,Q11,Q10. Each phase:
//   {setprio(1) MFMA(regs read >=1 phase ago) setprio(0); VMW(6); ds_reads(next); stage; BAR}
// Reads: P1: B1(t) [use P2]; P2: A1(t) [use P3]; P3: none; P4: A0,B0(t+1) from buf^1 [use P1'].
// Staging: P1: AS1(t+1)->buf^1; P2: AS0(t+2); P3: BS0(t+2); P4: BS1(t+2).
// Uniform VMW(6): 6-8 loads in flight; each phase's drain covers the read 1+ phase later.

#define BAR()   __builtin_amdgcn_s_barrier()
#define VMW(N)  asm volatile("s_waitcnt vmcnt(" #N ")" ::: "memory")

#define STAGE2(gXb, XsBuf, rb, kk) \
    async_copy16(gXb + (size_t)(rb) * K + (kk), (void*)&XsBuf[(rb) * 64])

#define ST_AS0(b, kk) { STAGE2(gAb, As[b], rbA_0, kk);      STAGE2(gAb, As[b], rbA_1, kk); }
#define ST_AS1(b, kk) { STAGE2(gAb, As[b], rbA_0 + 64, kk); STAGE2(gAb, As[b], rbA_1 + 64, kk); }
#define ST_BS0(b, kk) { STAGE2(gBb, Bs[b], rbB_0, kk);      STAGE2(gBb, Bs[b], rbB_1, kk); }
#define ST_BS1(b, kk) { STAGE2(gBb, Bs[b], rbB_0 + 32, kk); STAGE2(gBb, Bs[b], rbB_1 + 32, kk); }

#define READ_A(b, mh) \
    _Pragma("unroll") \
    for (int mm_ = 0; mm_ < 4; ++mm_) { \
        const unsigned short* ap_ = &As[b][(wr * 128 + (mh) * 64 + mm_ * 16 + fr) * 64]; \
        Ar[mm_][0] = *(const s16x8*)(ap_ + rofs0); \
        Ar[mm_][1] = *(const s16x8*)(ap_ + rofs1); \
    }

#define READ_B(b, nh, Brg) \
    _Pragma("unroll") \
    for (int nn_ = 0; nn_ < 2; ++nn_) { \
        const unsigned short* bp_ = &Bs[b][(wc * 64 + (nh) * 32 + nn_ * 16 + fr) * 64]; \
        Brg[nn_][0] = *(const s16x8*)(bp_ + rofs0); \
        Brg[nn_][1] = *(const s16x8*)(bp_ + rofs1); \
    }

#define MFMA_Q(mh, nh, Brg) \
    _Pragma("unroll") \
    for (int mm_ = 0; mm_ < 4; ++mm_) { \
        _Pragma("unroll") \
        for (int nn_ = 0; nn_ < 2; ++nn_) { \
            acc[(mh) * 4 + mm_][(nh) * 2 + nn_] = __builtin_amdgcn_mfma_f32_16x16x32_bf16( \
                Ar[mm_][0], Brg[nn_][0], acc[(mh) * 4 + mm_][(nh) * 2 + nn_], 0, 0, 0); \
            acc[(mh) * 4 + mm_][(nh) * 2 + nn_] = __builtin_amdgcn_mfma_f32_16x16x32_bf16( \
                Ar[mm_][1], Brg[nn_][1], acc[(mh) * 4 + mm_][(nh) * 2 + nn_], 0, 0, 0); \
        } \
    }

#define GROUP(b, t) { \
    int x1_ = (t) + 1; if (x1_ >= ktiles) x1_ -= ktiles; \
    int x2_ = (t) + 2; if (x2_ >= ktiles) x2_ -= ktiles; \
    const int kn1 = x1_ << 6; \
    const int kn2 = x2_ << 6; \
    /* P1: Q00 (A0 x B0, regs from P4(t-1)); read B1(t); stage AS1(t+1) */ \
    __builtin_amdgcn_s_setprio(1); MFMA_Q(0, 0, Br0); __builtin_amdgcn_s_setprio(0); \
    VMW(6); \
    READ_B(b, 1, Br1); \
    ST_AS1((b) ^ 1, kn1); \
    BAR(); \
    /* P2: Q01 (A0 x B1); read A1(t) (frees A0 after MFMA); stage AS0(t+2) */ \
    __builtin_amdgcn_s_setprio(1); MFMA_Q(0, 1, Br1); __builtin_amdgcn_s_setprio(0); \
    VMW(6); \
    READ_A(b, 1); \
    ST_AS0(b, kn2); \
    BAR(); \
    /* P3: Q11 (A1 x B1); stage BS0(t+2) */ \
    __builtin_amdgcn_s_setprio(1); MFMA_Q(1, 1, Br1); __builtin_amdgcn_s_setprio(0); \
    VMW(6); \
    ST_BS0(b, kn2); \
    BAR(); \
    /* P4: Q10 (A1 x B0); read A0,B0 of tile t+1 from buf^1; stage BS1(t+2) */ \
    __builtin_amdgcn_s_setprio(1); MFMA_Q(1, 0, Br0); __builtin_amdgcn_s_setprio(0); \
    VMW(6); \
    READ_A((b) ^ 1, 0); \
    READ_B((b) ^ 1, 0, Br0); \
    ST_BS1(b, kn2); \
    BAR(); \
}

__global__ __launch_bounds__(512, 2) void gemm256_bt(const unsigned short* __restrict__ A,
                                                     const unsigned short* __restrict__ B,
                                                     const float* __restrict__ bias,
                                                     unsigned short* __restrict__ C,
                                                     int M, int N, int K) {
    __shared__ unsigned short As[2][256 * 64];   // 64 KB
    __shared__ unsigned short Bs[2][256 * 64];   // 64 KB
    const int tid  = threadIdx.x;
    const int lane = tid & 63;
    const int wv   = tid >> 6;      // 0..7
    const int wr   = wv >> 2;       // 0..1 (M-half)
    const int wc   = wv & 3;        // 0..3 (N-quarter)
    // XCD-aware chunked mapping (round-robin dispatch: xcd = bid&7).
    // Each XCD: 2 A-strips x 15 B-panels; each B-panel shared by 2 co-XCD blocks.
    const int j     = blockIdx.x & 7;
    const int local = blockIdx.x >> 3;
    const int strip = 2 * (j & 3) + (local & 1);
    const int panel = (j >> 2) * 15 + (local >> 1);
    const int m0 = strip * 256;
    const int n0 = panel * 256;
    const int fr = lane & 15;
    const int fg = lane >> 4;
    const int rofs0 = (fg ^ (fr & 7)) * 8;
    const int rofs1 = rofs0 ^ 32;
    // staging: lane covers row (lane>>3), fetches global chunk (lane&7)^((lane>>3)&7)
    const int rlane = lane >> 3;
    const int swzc  = ((lane & 7) ^ (rlane & 7)) * 8;
    const int idx0 = wv * 2, idx1 = wv * 2 + 1;
    const int rbA_0 = idx0 * 8 + ((idx0 >= 8) ? 64 : 0);  // A-S0 row bases
    const int rbA_1 = idx1 * 8 + ((idx1 >= 8) ? 64 : 0);
    const int rbB_0 = (idx0 >> 2) * 64 + (idx0 & 3) * 8;  // B-S0 row bases
    const int rbB_1 = (idx1 >> 2) * 64 + (idx1 & 3) * 8;
    const int ktiles = K >> 6;      // 40

    const unsigned short* gAb = A + (size_t)(m0 + rlane) * K + swzc;
    const unsigned short* gBb = B + (size_t)(n0 + rlane) * K + swzc;

    f32x4 acc[8][4];
    const f32x4 zf = {0.f, 0.f, 0.f, 0.f};
#pragma unroll
    for (int i = 0; i < 8; ++i)
#pragma unroll
        for (int jj = 0; jj < 4; ++jj) acc[i][jj] = zf;

    s16x8 Ar[4][2], Br0[2][2], Br1[2][2];

    // prologue: tile0 complete + tile1 {AS0, BS0, BS1} (AS1(1) comes in P1 of GROUP 0);
    // drain tile0 (VMW(6) leaves tile1's 6 in flight); pre-read A0(t0), B0(t0).
    ST_AS0(0, 0); ST_AS1(0, 0); ST_BS0(0, 0); ST_BS1(0, 0);
    ST_AS0(1, 64); ST_BS0(1, 64); ST_BS1(1, 64);
    VMW(6);
    BAR();
    READ_A(0, 0);
    READ_B(0, 0, Br0);

    const int nit = ktiles >> 1;
    for (int it = 0; it < nit; ++it) {
        GROUP(0, it * 2);
        GROUP(1, it * 2 + 1);
    }

    // epilogue: C/D layout col=lane&15, row=(lane>>4)*4+reg
    const int rb = (lane >> 4) * 4;
#pragma unroll
    for (int nn = 0; nn < 4; ++nn) {
        int col = n0 + wc * 64 + nn * 16 + fr;
        float bv = bias[col];
#pragma unroll
        for (int mm = 0; mm < 8; ++mm) {
            int row = m0 + wr * 128 + mm * 16 + rb;
#pragma unroll
            for (int q = 0; q < 4; ++q) {
                float v = acc[mm][nn][q] + bv;
                C[(size_t)(row + q) * N + col] = f2bf(v);
            }
        }
    }
}

// ---------------- RoPE in-place on q-half only (k handled in rope_pack_k) ----------------
__global__ __launch_bounds__(256) void rope_q_kernel(unsigned short* __restrict__ qkv) {
    int g = blockIdx.x * 256 + threadIdx.x;  // 2048*32*2 items
    int c = g & 1;            // half-chunk: pairs d0..d0+7
    int h = (g >> 1) & 31;
    int p = g >> 6;
    size_t base = (size_t)p * 7680 + h * 80 + c * 8;
    s16x8 x1v = *(const s16x8*)(qkv + base);
    s16x8 x2v = *(const s16x8*)(qkv + base + 16);
    s16x8 o1, o2;
    for (int j = 0; j < 8; ++j) {
        int dp = c * 8 + j;
        float freq = expf(-(float)dp * 0.57564627324851142f);  // ln(10000)/16
        float sn, cs;
        sincosf((float)p * freq, &sn, &cs);
        float x1 = bf2f((unsigned short)x1v[j]);
        float x2 = bf2f((unsigned short)x2v[j]);
        o1[j] = (short)f2bf(x1 * cs - x2 * sn);
        o2[j] = (short)f2bf(x1 * sn + x2 * cs);
    }
    *(s16x8*)(qkv + base)      = o1;
    *(s16x8*)(qkv + base + 16) = o2;
}

// ---------------- fused k-RoPE + pack: qkv k-half -> Kp[h][u32][12][32][8] ----------------
// Chunk-major per 32-key tile so flash can (a) stage linearly with global_load_lds and
// (b) read MFMA fragments from LDS at the bank-throughput floor.
__global__ __launch_bounds__(256) void rope_pack_k_kernel(const unsigned short* __restrict__ qkv,
                                                          unsigned short* __restrict__ Kp) {
    int g = blockIdx.x * 256 + threadIdx.x;  // 2048*32*12
    int c   = g % 12;
    int h   = (g / 12) & 31;
    int pos = g / 384;
    int d0 = c * 8;
    const unsigned short* kb = qkv + (size_t)pos * 7680 + 2560 + h * 80;
    s16x8 v = {0, 0, 0, 0, 0, 0, 0, 0};
    if (c >= 4) {
        if (d0 < 80) v = *(const s16x8*)(kb + d0);
    } else if (c < 2) {          // x1 side: out = x1*cos - x2*sin
        s16x8 x1v = *(const s16x8*)(kb + d0);
        s16x8 x2v = *(const s16x8*)(kb + d0 + 16);
        for (int j = 0; j < 8; ++j) {
            int dp = d0 + j;
            float freq = expf(-(float)dp * 0.57564627324851142f);
            float sn, cs;
            sincosf((float)pos * freq, &sn, &cs);
            v[j] = (short)f2bf(bf2f((unsigned short)x1v[j]) * cs -
                               bf2f((unsigned short)x2v[j]) * sn);
        }
    } else {                     // x2 side: out = x1*sin + x2*cos
        s16x8 x1v = *(const s16x8*)(kb + d0 - 16);
        s16x8 x2v = *(const s16x8*)(kb + d0);
        for (int j = 0; j < 8; ++j) {
            int dp = d0 - 16 + j;
            float freq = expf(-(float)dp * 0.57564627324851142f);
            float sn, cs;
            sincosf((float)pos * freq, &sn, &cs);
            v[j] = (short)f2bf(bf2f((unsigned short)x1v[j]) * sn +
                               bf2f((unsigned short)x2v[j]) * cs);
        }
    }
    *(s16x8*)(Kp + (((size_t)h * 64 + (pos >> 5)) * 12 + c) * 256 + (pos & 31) * 8) = v;
}

// ---------------- pack V^T tiled (key-permuted): qkv v-half -> Vp[h][kblk16][80][16] -------
// Within each 32-key unit, slot s holds TRUE key pi(s) = 16*((s&7)>>2) + (s>>3)*4 + (s&3).
// This matches flash v8's in-register P layout (pa[j] = pr[j>>2][j&3] at k-slot fg*8+j),
// so the PV MFMA pairs P[pi(s)] with V[pi(s)] — permutation cancels in the key-sum.
__global__ __launch_bounds__(256) void pack_v_kernel(const unsigned short* __restrict__ qkv,
                                                     unsigned short* __restrict__ Vp) {
    int h  = blockIdx.x & 31;
    int g64 = blockIdx.x >> 5;           // 0..31
    int k0 = g64 * 64;
    int tid = threadIdx.x;
    for (int ci = tid; ci < 320; ci += 256) {   // (kbl 0..3) x (d 0..79)
        int d   = ci % 80;
        int kbl = ci / 80;
        unsigned short tmp[16];
        for (int j = 0; j < 16; ++j) {
            int s  = (kbl & 1) * 16 + j;                       // slot within 32-key unit
            int kt = ((s & 7) >> 2) * 16 + (s >> 3) * 4 + (s & 3);  // true key (pi)
            tmp[j] = qkv[(size_t)(k0 + (kbl >> 1) * 32 + kt) * 7680 + 5120 + h * 80 + d];
        }
        unsigned short* dst = Vp + ((size_t)h * 128 + g64 * 4 + kbl) * 1280 + d * 16;
        *(s16x8*)dst       = *(const s16x8*)&tmp[0];
        *(s16x8*)(dst + 8) = *(const s16x8*)&tmp[8];
    }
}

// ---------------- flash attention v8: swapped QK + fully in-register P ----------
// v7 structure (8 strips/block, wave pair, LDS K/V dbuf, hoisted K/V reads) with the
// P-LDS path eliminated: QK computed SWAPPED (mfma(K,Q)) so lane (fr,fg) holds
// P[q=fr][key=g*16+fg*4+r]; with pi-permuted V (pack_v), pa[j]=pr[j>>2][j&3] feeds PV
// directly — 4 bit-op packs replace 8 ds_write+1 ds_read+lgkm chain per FSTEP (pack is
// the same >>16 truncation previous rounds used, so P bits are identical). Row-sums are
// per-lane scalars (q=fr), reduced once at the end (2x shfl_xor + shfl broadcast).
__global__ __launch_bounds__(256) void flash8_kernel(const unsigned short* __restrict__ qkv,
                                                     const unsigned short* __restrict__ Kp,
                                                     const unsigned short* __restrict__ Vp,
                                                     unsigned short* __restrict__ attn) {
    __shared__ unsigned short Ks[2][3072];     // 32 keys x 96 dims (chunk-major [12][32][8])
    __shared__ unsigned short Vs[2][2560];     // 2 x [80][16] V tiles (pi-permuted keys)
    const int tid  = threadIdx.x;
    const int lane = tid & 63;
    const int wv   = tid >> 6;
    const int h  = blockIdx.x & 31;
    const int jj = blockIdx.x >> 5;            // 0..15
    const int fr = lane & 15;
    const int fg = lane >> 4;
    const float k1 = 0.11180339887498949f * LOG2E;  // (1/sqrt(80)) * log2(e)

    const int sA  = jj + 16 * wv;
    const int sB  = jj + 112 - 16 * wv;
    const int smA = sA * 16;
    const int smB = sB * 16;
    const int Ublk = (jj + 114) >> 1;          // units covering the longest strip (jj+112)

    const s16x8 zs = {0, 0, 0, 0, 0, 0, 0, 0};
    s16x8 qfA[3], qfB[3];
    {
        const unsigned short* qa = qkv + (size_t)(smA + fr) * 7680 + h * 80;
        const unsigned short* qb = qkv + (size_t)(smB + fr) * 7680 + h * 80;
        for (int sd = 0; sd < 3; ++sd) {
            int d = 32 * sd + fg * 8;
            qfA[sd] = (d < 80) ? *(const s16x8*)(qa + d) : zs;
            qfB[sd] = (d < 80) ? *(const s16x8*)(qb + d) : zs;
        }
    }

    f32x4 OA[5], OB[5];
    const f32x4 zf = {0.f, 0.f, 0.f, 0.f};
    for (int t = 0; t < 5; ++t) { OA[t] = zf; OB[t] = zf; }
    float rsA = 0.f, rsB = 0.f;

    const unsigned short* Kh = Kp + (size_t)h * 196608;   // 64 tiles * 3072
    const unsigned short* Vh = Vp + (size_t)h * 163840;   // 128 blk * 1280

    // chunk q (0..10): q<6 -> K 1KB chunk q; else V 1KB chunk q-6. Wave w: {w, w+4, w+8}.
#define STG1(q, b, uu) { \
    if ((q) < 6) async_copy16(Kh + (size_t)(uu) * 3072 + (q) * 512 + lane * 8, &Ks[b][(q) * 512]); \
    else         async_copy16(Vh + (size_t)(uu) * 2560 + ((q) - 6) * 512 + lane * 8, &Vs[b][((q) - 6) * 512]); }
#define STAGEU(b, uu) { STG1(wv, b, uu); STG1(wv + 4, b, uu); if (wv < 3) STG1(wv + 8, b, uu); }

    // swapped softmax: mask, exp, scalar rowsum, lane-local pack into PV A-fragment
    // (pack = truncating >>16, bit-identical to the LDS path of previous rounds)
#define SMX8(SA, RS, SM16, K0, PA) { \
    if ((K0) + 32 > (SM16)) { \
        _Pragma("unroll") \
        for (int g = 0; g < 2; ++g) \
            _Pragma("unroll") \
            for (int r = 0; r < 4; ++r) { \
                int key  = (K0) + g * 16 + fg * 4 + r; \
                int qrow = (SM16) + fr; \
                if (key > qrow) SA[g][r] = -1e30f; \
            } \
    } \
    float pr[2][4]; \
    _Pragma("unroll") \
    for (int g = 0; g < 2; ++g) \
        _Pragma("unroll") \
        for (int r = 0; r < 4; ++r) \
            pr[g][r] = __builtin_amdgcn_exp2f(SA[g][r] * k1); \
    RS += (pr[0][0] + pr[0][1]) + (pr[0][2] + pr[0][3]) \
        + (pr[1][0] + pr[1][1]) + (pr[1][2] + pr[1][3]); \
    u32x4 pw_; \
    _Pragma("unroll") \
    for (int g = 0; g < 2; ++g) \
        _Pragma("unroll") \
        for (int q2 = 0; q2 < 2; ++q2) { \
            unsigned int u0 = __float_as_uint(pr[g][q2 * 2]); \
            unsigned int u1 = __float_as_uint(pr[g][q2 * 2 + 1]); \
            pw_[g * 2 + q2] = (u0 >> 16) | (u1 & 0xFFFF0000u); \
        } \
    PA = __builtin_bit_cast(s16x8, pw_); }

    STAGEU(0, 0);
    __syncthreads();          // full drain: unit-0 tiles resident
    int buf = 0;
    for (int u = 0; u < Ublk; ++u) {
        if (u + 1 < Ublk) STAGEU(buf ^ 1, u + 1);   // async issue; drained by the syncthreads below
        const int k0 = u * 32;
        const bool actA = (2 * u <= sA);            // sB >= sA: actB covers "any active"
        const bool actB = (2 * u <= sB);
        if (actB) {
            // hoisted K/V fragment reads — shared by both strips (same unit tile)
            s16x8 kb[2][3];
#pragma unroll
            for (int g = 0; g < 2; ++g)
#pragma unroll
                for (int sd = 0; sd < 3; ++sd)
                    kb[g][sd] = *(const s16x8*)&Ks[buf][(fg + sd * 4) * 256 + (g * 16 + fr) * 8];
            s16x8 vb[5];
#pragma unroll
            for (int t = 0; t < 5; ++t)
                vb[t] = *(const s16x8*)&Vs[buf][(fg >> 1) * 1280 + t * 256 + fr * 16 + (fg & 1) * 8];

            f32x4 saA[2] = {zf, zf};
            f32x4 saB[2] = {zf, zf};
            __builtin_amdgcn_s_setprio(1);
            if (actA) {
#pragma unroll
                for (int g = 0; g < 2; ++g)
#pragma unroll
                    for (int sd = 0; sd < 3; ++sd)
                        saA[g] = __builtin_amdgcn_mfma_f32_16x16x32_bf16(kb[g][sd], qfA[sd], saA[g], 0, 0, 0);
            }
#pragma unroll
            for (int g = 0; g < 2; ++g)
#pragma unroll
                for (int sd = 0; sd < 3; ++sd)
                    saB[g] = __builtin_amdgcn_mfma_f32_16x16x32_bf16(kb[g][sd], qfB[sd], saB[g], 0, 0, 0);
            __builtin_amdgcn_s_setprio(0);

            s16x8 paA, paB;
            if (actA) SMX8(saA, rsA, smA, k0, paA);
            SMX8(saB, rsB, smB, k0, paB);

            __builtin_amdgcn_s_setprio(1);
            if (actA) {
#pragma unroll
                for (int t = 0; t < 5; ++t)
                    OA[t] = __builtin_amdgcn_mfma_f32_16x16x32_bf16(paA, vb[t], OA[t], 0, 0, 0);
            }
#pragma unroll
            for (int t = 0; t < 5; ++t)
                OB[t] = __builtin_amdgcn_mfma_f32_16x16x32_bf16(paB, vb[t], OB[t], 0, 0, 0);
            __builtin_amdgcn_s_setprio(0);
        }
        __syncthreads();      // drains vmcnt (stage done) + lgkm (reads done) before overwrite
        buf ^= 1;
    }
#undef STG1
#undef STAGEU
#undef SMX8

    // epilogue: rowsum lives per-lane at q=fr; reduce over fg groups, broadcast to q=fg*4+r
#define FIN8(RS, OO, SM16) { \
    RS += __shfl_xor(RS, 16); \
    RS += __shfl_xor(RS, 32); \
    _Pragma("unroll") \
    for (int r = 0; r < 4; ++r) { \
        float rl = 1.0f / __shfl(RS, fg * 4 + r); \
        int row = (SM16) + fg * 4 + r; \
        _Pragma("unroll") \
        for (int t = 0; t < 5; ++t) \
            attn[(size_t)row * 2560 + h * 80 + t * 16 + fr] = f2bf(OO[t][r] * rl); \
    } }
    FIN8(rsA, OA, smA);
    FIN8(rsB, OB, smB);
#undef FIN8
}

extern "C" void kernel_launch(void* const* d_in, const int* in_sizes, int n_in,
                              void* d_out, int out_size, void* d_ws, size_t ws_size,
                              hipStream_t stream) {
    const float* x    = (const float*)d_in[0];
    const float* wqkv = (const float*)d_in[1];
    const float* bqkv = (const float*)d_in[2];
    const float* outw = (const float*)d_in[3];
    const float* outb = (const float*)d_in[4];

    unsigned short* xb    = (unsigned short*)d_ws;                  // 2048*2560
    unsigned short* wqkvb = xb + (size_t)2048 * 2560;               // 7680*2560 (dead after gemm1)
    unsigned short* Kp    = wqkvb;                                  // 32*64*12*32*8 (aliases wqkvb)
    unsigned short* Vp    = wqkvb + (size_t)32 * 2048 * 96;         // 32*128*1280  (aliases wqkvb)
    unsigned short* outwb = wqkvb + (size_t)7680 * 2560;            // 2560*2560
    unsigned short* qkvb  = outwb + (size_t)2560 * 2560;            // 2048*7680
    unsigned short* attnb = qkvb  + (size_t)2048 * 7680;            // 2048*2560
    float* out = (float*)d_out;

    cast_bf16_kernel<<<2048 * 2560 / 4 / 256, 256, 0, stream>>>(x, xb, 2048 * 2560 / 4);
    cast_bf16_kernel<<<7680 * 2560 / 4 / 256, 256, 0, stream>>>(wqkv, wqkvb, 7680 * 2560 / 4);
    cast_bf16_kernel<<<2560 * 2560 / 4 / 256, 256, 0, stream>>>(outw, outwb, 2560 * 2560 / 4);

    // qkv projection: 256x256 v3 pipeline, 240 blocks, XCD-chunked panel-sharing map
    gemm256_bt<<<240, 512, 0, stream>>>(xb, wqkvb, bqkv, qkvb, 2048, 7680, 2560);

    rope_q_kernel<<<2048 * 64 / 256, 256, 0, stream>>>(qkvb);
    rope_pack_k_kernel<<<2048 * 384 / 256, 256, 0, stream>>>(qkvb, Kp);
    pack_v_kernel<<<32 * 32, 256, 0, stream>>>(qkvb, Vp);

    // 512 blocks = 32 heads x 16 strip-octets; K/V shared across 128 q-rows per block
    flash8_kernel<<<512, 256, 0, stream>>>(qkvb, Kp, Vp, attnb);

    gemm_bt<false><<<dim3(2560 / 128, 2048 / 128), 256, 0, stream>>>(
        attnb, outwb, outb, (void*)out, 2048, 2560, 2560);
}